// Round 5
// baseline (196.671 us; speedup 1.0000x reference)
//
#include <hip/hip_runtime.h>
#include <hip/hip_bf16.h>
#include <math.h>

// SelfAttention: out = softmax(mask(q k^T)/32) v, q=xWq^T k=xWk^T v=xWv^T
// N=4096 tokens, E=1024. bf16 MFMA compute, fp32 accumulate.
// R5: 256^2-tile 8-wave 8-phase-style GEMM with T2 LDS XOR-swizzle +
//     T4 counted vmcnt (tile t+1 loads in flight across tile t) + T5 setprio.
//     PV split-K x4. All GEMM K-extents = 1024 (16 tiles of BK=64).

typedef __attribute__((ext_vector_type(8))) __bf16 bf16x8;
typedef __attribute__((ext_vector_type(4))) __bf16 bf16x4;
typedef __attribute__((ext_vector_type(4))) float f32x4;

__device__ __forceinline__ void gload_lds16(const void* g, void* l) {
  __builtin_amdgcn_global_load_lds(
      (__attribute__((address_space(1))) void*)(g),
      (__attribute__((address_space(3))) void*)(l), 16, 0, 0);
}

#define WAITB(N) asm volatile("s_waitcnt vmcnt(" #N ")\ns_barrier" ::: "memory")
#define BAR()    asm volatile("s_barrier" ::: "memory")

// Stage one 256x64 (A) or 256x64 (B) bf16 tile: 2048 16B-chunks, 4 per thread.
// T2 swizzle: physical chunk p holds logical (row=p>>3, cg=(p&7)^(row&7)).
// LDS dest linear (wave-uniform base + lane*16, rule 21); source pre-swizzled.
__device__ __forceinline__ void g8_stage(const __bf16* __restrict__ src, long ld,
                                         long r0, int k0, __bf16* dst, int tid) {
#pragma unroll
  for (int j = 0; j < 4; ++j) {
    int p = tid + j * 512;
    int row = p >> 3;
    int cg = (p & 7) ^ (row & 7);
    gload_lds16(src + (r0 + row) * ld + k0 + cg * 8, dst + p * 8);
  }
}

// Swizzled LDS read address (elems): chunk = r*8 + (cc ^ (r&7)), r&7 == lo&7.
#define LDA8(sAc, kkc)                                                        \
  _Pragma("unroll") for (int m = 0; m < 8; ++m) {                             \
    int r = wr * 128 + m * 16 + lo;                                           \
    af[m] = *(const bf16x8*)((sAc) + r * 64 + (((hi + ((kkc) >> 3)) ^ (lo & 7)) * 8)); \
  }
#define LDB2(sBc, kkc, nh)                                                    \
  _Pragma("unroll") for (int n = 0; n < 2; ++n) {                             \
    int r = wc * 64 + ((nh)*2 + n) * 16 + lo;                                 \
    bf2[n] = *(const bf16x8*)((sBc) + r * 64 + (((hi + ((kkc) >> 3)) ^ (lo & 7)) * 8)); \
  }
#define MM(nh)                                                                \
  __builtin_amdgcn_s_setprio(1);                                              \
  _Pragma("unroll") for (int m = 0; m < 8; ++m)                               \
    _Pragma("unroll") for (int n = 0; n < 2; ++n)                             \
      acc[m][(nh)*2 + n] = __builtin_amdgcn_mfma_f32_16x16x32_bf16(           \
          af[m], bf2[n], acc[m][(nh)*2 + n], 0, 0, 0);                        \
  __builtin_amdgcn_s_setprio(0);

// Main loop: 256x256 tile, BK=64, NT=16 K-tiles, 8 waves (2Mx4N), per-wave
// C = 128x64 (8x4 frags). Double-buffered LDS (128KB). Counted-vmcnt pipeline:
// stage t+2 after tile t's read-done barrier; WAITB(8) leaves t+2's 8 loads
// in flight while guaranteeing t+1 landed (in-order vmcnt retire).
__device__ __forceinline__ void g8_loop(const __bf16* __restrict__ A, long lda, long row0,
                                        const __bf16* __restrict__ B, long ldb, long col0,
                                        int kstart, __bf16* sA, __bf16* sB,
                                        f32x4 (&acc)[8][4], int tid) {
  const int lane = tid & 63, w = tid >> 6;
  const int wr = w >> 2, wc = w & 3;
  const int lo = lane & 15, hi = lane >> 4;
  const int NT = 16;

  g8_stage(A, lda, row0, kstart, sA, tid);
  g8_stage(B, ldb, col0, kstart, sB, tid);
  g8_stage(A, lda, row0, kstart + 64, sA + 16384, tid);
  g8_stage(B, ldb, col0, kstart + 64, sB + 16384, tid);
  WAITB(8);  // tile0 landed; tile1 in flight

  for (int t = 0; t < NT; ++t) {
    const int d = t & 1;
    const __bf16* sAc = sA + d * 16384;
    const __bf16* sBc = sB + d * 16384;
    bf16x8 af[8], bf2[2];
    // ph0: (kk=0, n01)
    LDA8(sAc, 0); LDB2(sBc, 0, 0);
    BAR(); MM(0); BAR();
    // ph1: (kk=0, n23)
    LDB2(sBc, 0, 1);
    BAR(); MM(1); BAR();
    // ph2: (kk=32, n01)
    LDA8(sAc, 32); LDB2(sBc, 32, 0);
    BAR(); MM(0); BAR();
    // ph3: (kk=32, n23)
    LDB2(sBc, 32, 1);
    BAR(); MM(1); BAR();
    // All waves done reading buf d -> restage it for tile t+2.
    if (t + 2 < NT) {
      g8_stage(A, lda, row0, kstart + (t + 2) * 64, sA + d * 16384, tid);
      g8_stage(B, ldb, col0, kstart + (t + 2) * 64, sB + d * 16384, tid);
      WAITB(8);   // t+1 ready; t+2's loads stay in flight
    } else {
      WAITB(0);   // tail: drain (t+1 ready / final no-op)
    }
  }
}

// ---------------- kernels ----------------

__global__ __launch_bounds__(512) void qkv8(const __bf16* __restrict__ xb,
                                            const __bf16* __restrict__ wq,
                                            const __bf16* __restrict__ wk,
                                            const __bf16* __restrict__ wv,
                                            __bf16* __restrict__ qb,
                                            __bf16* __restrict__ kb,
                                            __bf16* __restrict__ vtb) {
  __shared__ __bf16 sA[2 * 16384];
  __shared__ __bf16 sB[2 * 16384];
  const int raw = blockIdx.x;
  const int wid = (raw & 7) * 24 + (raw >> 3);   // nwg=192, bijective
  const int z = wid >> 6;
  const int r2 = wid & 63;
  const long row0 = (long)(r2 >> 2) * 256;       // token tile (16)
  const long col0 = (long)(r2 & 3) * 256;        // feature tile (4)
  const __bf16* Bw = (z == 0) ? wq : (z == 1) ? wk : wv;
  f32x4 acc[8][4] = {};
  g8_loop(xb, 1024, row0, Bw, 1024, col0, 0, sA, sB, acc, threadIdx.x);

  const int lane = threadIdx.x & 63, w = threadIdx.x >> 6;
  const int wr = w >> 2, wc = w & 3;
  const int lo = lane & 15, hi = lane >> 4;
#pragma unroll
  for (int m = 0; m < 8; ++m)
#pragma unroll
    for (int n = 0; n < 4; ++n)
#pragma unroll
      for (int i = 0; i < 4; ++i) {
        long r = row0 + wr * 128 + m * 16 + hi * 4 + i;
        long c = col0 + wc * 64 + n * 16 + lo;
        __bf16 v = (__bf16)acc[m][n][i];
        if (z == 0)      qb[r * 1024 + c] = v;
        else if (z == 1) kb[r * 1024 + c] = v;
        else             vtb[c * 4096 + r] = v;   // v stored transposed
      }
}

__global__ __launch_bounds__(512) void qk8(const __bf16* __restrict__ qb,
                                           const __bf16* __restrict__ kb,
                                           __bf16* __restrict__ sim) {
  __shared__ __bf16 sA[2 * 16384];
  __shared__ __bf16 sB[2 * 16384];
  const int raw = blockIdx.x;
  const int wid = (raw & 7) * 32 + (raw >> 3);   // nwg=256, bijective
  const long row0 = (long)(wid >> 4) * 256;
  const long col0 = (long)(wid & 15) * 256;
  f32x4 acc[8][4] = {};
  g8_loop(qb, 1024, row0, kb, 1024, col0, 0, sA, sB, acc, threadIdx.x);

  const int lane = threadIdx.x & 63, w = threadIdx.x >> 6;
  const int wr = w >> 2, wc = w & 3;
  const int lo = lane & 15, hi = lane >> 4;
#pragma unroll
  for (int m = 0; m < 8; ++m)
#pragma unroll
    for (int n = 0; n < 4; ++n)
#pragma unroll
      for (int i = 0; i < 4; ++i) {
        long r = row0 + wr * 128 + m * 16 + hi * 4 + i;
        long c = col0 + wc * 64 + n * 16 + lo;
        sim[r * 4096 + c] = (__bf16)acc[m][n][i];
      }
}

// PV split-K x4: z -> K window [z*1024, z*1024+1024). z=0 -> out, else p[z].
__global__ __launch_bounds__(512) void pv8(const __bf16* __restrict__ attn,
                                           const __bf16* __restrict__ vt,
                                           float* __restrict__ out,
                                           float* __restrict__ p1,
                                           float* __restrict__ p2,
                                           float* __restrict__ p3) {
  __shared__ __bf16 sA[2 * 16384];
  __shared__ __bf16 sB[2 * 16384];
  const int raw = blockIdx.x;
  const int wid = (raw & 7) * 32 + (raw >> 3);   // nwg=256, bijective
  const int z = wid >> 6;
  const int r2 = wid & 63;
  const long row0 = (long)(r2 >> 2) * 256;       // token tile (16)
  const long col0 = (long)(r2 & 3) * 256;        // feature tile (4)
  float* C = (z == 0) ? out : (z == 1) ? p1 : (z == 2) ? p2 : p3;
  f32x4 acc[8][4] = {};
  g8_loop(attn, 4096, row0, vt, 4096, col0, z * 1024, sA, sB, acc, threadIdx.x);

  const int lane = threadIdx.x & 63, w = threadIdx.x >> 6;
  const int wr = w >> 2, wc = w & 3;
  const int lo = lane & 15, hi = lane >> 4;
#pragma unroll
  for (int m = 0; m < 8; ++m)
#pragma unroll
    for (int n = 0; n < 4; ++n)
#pragma unroll
      for (int i = 0; i < 4; ++i) {
        long r = row0 + wr * 128 + m * 16 + hi * 4 + i;
        long c = col0 + wc * 64 + n * 16 + lo;
        C[r * 1024 + c] = acc[m][n][i];
      }
}

__global__ __launch_bounds__(256) void reduce_add4(float* __restrict__ out,
                                                   const float* __restrict__ a,
                                                   const float* __restrict__ b,
                                                   const float* __restrict__ c) {
  int i = blockIdx.x * 256 + threadIdx.x;  // 1,048,576 float4s
  float4 o = ((const float4*)out)[i];
  float4 x = ((const float4*)a)[i];
  float4 y = ((const float4*)b)[i];
  float4 z = ((const float4*)c)[i];
  o.x += x.x + y.x + z.x; o.y += x.y + y.y + z.y;
  o.z += x.z + y.z + z.z; o.w += x.w + y.w + z.w;
  ((float4*)out)[i] = o;
}

// One launch converts x, Wq, Wk, Wv to bf16. Blocks partitioned by range.
__global__ __launch_bounds__(256) void cvt_all(const float* __restrict__ x,
                                               const float* __restrict__ wq,
                                               const float* __restrict__ wk,
                                               const float* __restrict__ wv,
                                               __bf16* __restrict__ xb,
                                               __bf16* __restrict__ wqb,
                                               __bf16* __restrict__ wkb,
                                               __bf16* __restrict__ wvb) {
  int b = blockIdx.x;
  const float* in;
  __bf16* out;
  int base;
  if (b < 4096)      { in = x;  out = xb;  base = b; }
  else if (b < 5120) { in = wq; out = wqb; base = b - 4096; }
  else if (b < 6144) { in = wk; out = wkb; base = b - 5120; }
  else               { in = wv; out = wvb; base = b - 6144; }
  int i = base * 256 + threadIdx.x;
  float4 f = ((const float4*)in)[i];
  bf16x4 o;
  o[0] = (__bf16)f.x; o[1] = (__bf16)f.y; o[2] = (__bf16)f.z; o[3] = (__bf16)f.w;
  ((bf16x4*)out)[i] = o;
}

// One block per row of bf16 sim (ld 4096): mask (-1e20 where mask==0), stable
// softmax of row/32, write attn bf16 IN-PLACE.
__global__ __launch_bounds__(256) void softmax_rows(__bf16* __restrict__ sim,
                                                    const int* __restrict__ mask) {
  const int row = blockIdx.x;
  __bf16* rp = sim + (size_t)row * 4096;
  const int4* mrow = (const int4*)(mask + (size_t)row * 4096);
  const int tid = threadIdx.x;

  float vals[16];
  float lmax = -INFINITY;
#pragma unroll
  for (int j = 0; j < 2; ++j) {
    bf16x8 s = ((const bf16x8*)rp)[tid + 256 * j];
    int4 m0 = mrow[(tid + 256 * j) * 2];
    int4 m1 = mrow[(tid + 256 * j) * 2 + 1];
    float f[8];
#pragma unroll
    for (int e = 0; e < 8; ++e) f[e] = (float)s[e];
    f[0] = m0.x ? f[0] : -1e20f;  f[1] = m0.y ? f[1] : -1e20f;
    f[2] = m0.z ? f[2] : -1e20f;  f[3] = m0.w ? f[3] : -1e20f;
    f[4] = m1.x ? f[4] : -1e20f;  f[5] = m1.y ? f[5] : -1e20f;
    f[6] = m1.z ? f[6] : -1e20f;  f[7] = m1.w ? f[7] : -1e20f;
#pragma unroll
    for (int e = 0; e < 8; ++e) {
      vals[8 * j + e] = f[e];
      lmax = fmaxf(lmax, f[e]);
    }
  }
#pragma unroll
  for (int off = 32; off; off >>= 1) lmax = fmaxf(lmax, __shfl_xor(lmax, off));
  __shared__ float red[4];
  __shared__ float bro[2];
  if ((tid & 63) == 0) red[tid >> 6] = lmax;
  __syncthreads();
  if (tid == 0) bro[0] = fmaxf(fmaxf(red[0], red[1]), fmaxf(red[2], red[3]));
  __syncthreads();
  const float m = bro[0];

  float e[16];
  float lsum = 0.f;
#pragma unroll
  for (int j = 0; j < 16; ++j) {
    e[j] = __expf((vals[j] - m) * 0.03125f);  // /sqrt(1024)
    lsum += e[j];
  }
#pragma unroll
  for (int off = 32; off; off >>= 1) lsum += __shfl_xor(lsum, off);
  if ((tid & 63) == 0) red[tid >> 6] = lsum;
  __syncthreads();
  if (tid == 0) bro[1] = red[0] + red[1] + red[2] + red[3];
  __syncthreads();
  const float inv = 1.0f / bro[1];

#pragma unroll
  for (int j = 0; j < 2; ++j) {
    bf16x8 o;
#pragma unroll
    for (int q = 0; q < 8; ++q) o[q] = (__bf16)(e[8 * j + q] * inv);
    ((bf16x8*)rp)[tid + 256 * j] = o;
  }
}

extern "C" void kernel_launch(void* const* d_in, const int* in_sizes, int n_in,
                              void* d_out, int out_size, void* d_ws, size_t ws_size,
                              hipStream_t stream) {
  const float* x = (const float*)d_in[0];
  const int* mask = (const int*)d_in[1];
  const float* Wq = (const float*)d_in[2];
  const float* Wk = (const float*)d_in[3];
  const float* Wv = (const float*)d_in[4];
  float* out = (float*)d_out;

  // Workspace layout (102 MB, proven available in R1):
  // [0,8M)   vT bf16    [8,16M)  x bf16
  // [16,18M) Wq bf16    [18,20M) Wk bf16   [20,22M) Wv bf16
  // [22,30M) q bf16     [30,38M) k bf16
  // [38,70M) sim bf16 (attn in-place, ld 4096)
  // PV-time (x,W,q,k dead): p1 [8,24M), p2 [70,86M), p3 [86,102M)
  char* ws = (char*)d_ws;
  __bf16* vtb = (__bf16*)(ws);
  __bf16* xb  = (__bf16*)(ws + (8ull << 20));
  __bf16* wqb = (__bf16*)(ws + (16ull << 20));
  __bf16* wkb = (__bf16*)(ws + (18ull << 20));
  __bf16* wvb = (__bf16*)(ws + (20ull << 20));
  __bf16* qb  = (__bf16*)(ws + (22ull << 20));
  __bf16* kb  = (__bf16*)(ws + (30ull << 20));
  __bf16* sim = (__bf16*)(ws + (38ull << 20));
  float*  p1  = (float*)(ws + (8ull << 20));
  float*  p2  = (float*)(ws + (70ull << 20));
  float*  p3  = (float*)(ws + (86ull << 20));

  cvt_all<<<7168, 256, 0, stream>>>(x, Wq, Wk, Wv, xb, wqb, wkb, wvb);

  dim3 blk(512);
  // q, k, vT: 192 blocks of 256^2
  qkv8<<<192, blk, 0, stream>>>(xb, wqb, wkb, wvb, qb, kb, vtb);
  // sim = q k^T (4096x4096): 256 blocks
  qk8<<<256, blk, 0, stream>>>(qb, kb, sim);
  // masked softmax, attn bf16 in-place
  softmax_rows<<<4096, 256, 0, stream>>>(sim, mask);
  // out = attn vT^T, split-K x4: 256 blocks
  pv8<<<256, blk, 0, stream>>>(sim, vtb, out, p1, p2, p3);
  reduce_add4<<<4096, 256, 0, stream>>>(out, p1, p2, p3);
}

// Round 6
// 162.644 us; speedup vs baseline: 1.2092x; 1.2092x over previous
//
#include <hip/hip_runtime.h>
#include <hip/hip_bf16.h>
#include <math.h>

// SelfAttention: out = softmax(mask(q k^T)/32) v, q=xWq^T k=xWk^T v=xWv^T
// N=4096 tokens, E=1024. bf16 MFMA compute, fp32 accumulate.
// R6: BK=32 4-deep LDS pipeline (stage t+3 into guaranteed-free buffer,
//     2 loads/phase fine interleave, counted WAITB(8)); qkv z=2 operand
//     swap so vT is written coalesced (no 2B scatter).

typedef __attribute__((ext_vector_type(8))) __bf16 bf16x8;
typedef __attribute__((ext_vector_type(4))) __bf16 bf16x4;
typedef __attribute__((ext_vector_type(4))) float f32x4;

__device__ __forceinline__ void gload_lds16(const void* g, void* l) {
  __builtin_amdgcn_global_load_lds(
      (__attribute__((address_space(1))) void*)(g),
      (__attribute__((address_space(3))) void*)(l), 16, 0, 0);
}

#define WAITB(N) asm volatile("s_waitcnt vmcnt(" #N ")\ns_barrier" ::: "memory")

// ---- 256x256 tile, BK=32, 8 waves (2M x 4N), 4-deep LDS buffers ----
// Per K-tile: A 256x32 bf16 = 16KB = 1024 chunks(16B), 2/thread; same for B.
// Swizzle: physical chunk c of row r holds logical k-chunk c^(r&3).

// Stage one matrix half (j=0,1) of tile into buf: 1 load/thread each.
#define STQ_A(buf, j, kt)                                                   \
  { int p = tid + (j) * 512; int row = p >> 2; int cg = (p & 3) ^ (row & 3);\
    gload_lds16(A + (row0 + row) * lda + (kt) * 32 + cg * 8,                \
                sA + (buf) * 8192 + p * 8); }
#define STQ_B(buf, j, kt)                                                   \
  { int p = tid + (j) * 512; int row = p >> 2; int cg = (p & 3) ^ (row & 3);\
    gload_lds16(B + (col0 + row) * ldb + (kt) * 32 + cg * 8,                \
                sB + (buf) * 8192 + p * 8); }

// Swizzled ds_read of one bf16x8 fragment at (row r, k-chunk hi).
#define LDS_FRAG(base, r) \
  *(const bf16x8*)((base) + (r) * 32 + (((hi) ^ ((r) & 3)) * 8))

#define MM16(mq, AF)                                                        \
  __builtin_amdgcn_s_setprio(1);                                            \
  _Pragma("unroll") for (int m = 0; m < 4; ++m)                             \
    _Pragma("unroll") for (int n = 0; n < 4; ++n)                           \
      acc[(mq) * 4 + m][n] = __builtin_amdgcn_mfma_f32_16x16x32_bf16(       \
          AF[m], bfr[n], acc[(mq) * 4 + m][n], 0, 0, 0);                    \
  __builtin_amdgcn_s_setprio(0);

// kt0 = first K-tile index (K window start / 32). NT = 32 K-tiles (K=1024).
__device__ __forceinline__ void g8_loop(const __bf16* __restrict__ A, long lda, long row0,
                                        const __bf16* __restrict__ B, long ldb, long col0,
                                        int kt0, __bf16* sA, __bf16* sB,
                                        f32x4 (&acc)[8][4], int tid) {
  const int lane = tid & 63;
  const int w = tid >> 6;
  const int wr = w >> 2, wc = w & 3;
  const int lo = lane & 15, hi = lane >> 4;
  const int NT = 32;

  // Prologue: stage tiles 0,1,2 (4 loads each, A,A,B,B order per tile).
#pragma unroll
  for (int t = 0; t < 3; ++t) {
    STQ_A(t, 0, kt0 + t); STQ_A(t, 1, kt0 + t);
    STQ_B(t, 0, kt0 + t); STQ_B(t, 1, kt0 + t);
  }
  WAITB(8);  // tile0 landed; tiles 1,2 (8 loads) in flight

  for (int t = 0; t < NT; ++t) {
    const int d = t & 3;
    const __bf16* sAc = sA + d * 8192;
    const __bf16* sBc = sB + d * 8192;
    const int s = (t + 3) & 3;   // stage target buffer (free by construction)
    bf16x8 af[4], af2[4], bfr[4];
    // ph0: A-frags m0-3 + all B-frags; stage A half of t+3.
#pragma unroll
    for (int m = 0; m < 4; ++m) af[m] = LDS_FRAG(sAc, wr * 128 + m * 16 + lo);
#pragma unroll
    for (int n = 0; n < 4; ++n) bfr[n] = LDS_FRAG(sBc, wc * 64 + n * 16 + lo);
    if (t + 3 < NT) { STQ_A(s, 0, kt0 + t + 3); STQ_A(s, 1, kt0 + t + 3); }
    __builtin_amdgcn_s_barrier();
    MM16(0, af);
    __builtin_amdgcn_s_barrier();
    // ph1: A-frags m4-7; stage B half of t+3.
#pragma unroll
    for (int m = 0; m < 4; ++m) af2[m] = LDS_FRAG(sAc, wr * 128 + 64 + m * 16 + lo);
    if (t + 3 < NT) { STQ_B(s, 0, kt0 + t + 3); STQ_B(s, 1, kt0 + t + 3); }
    __builtin_amdgcn_s_barrier();
    MM16(1, af2);
    // tile-end: ensure t+1 landed; keep the rest in flight.
    if (t + 3 < NT)      { WAITB(8); }
    else if (t + 2 < NT) { WAITB(4); }
    else                 { WAITB(0); }
  }
}

// ---------------- kernels ----------------

// Fused QKV. z=0: q = x Wq^T; z=1: k = x Wk^T; z=2: vT = Wv x^T (operands
// swapped so the C-write is coalesced row-major in vT's token dim).
__global__ __launch_bounds__(512) void qkv8(const __bf16* __restrict__ xb,
                                            const __bf16* __restrict__ wq,
                                            const __bf16* __restrict__ wk,
                                            const __bf16* __restrict__ wv,
                                            __bf16* __restrict__ qb,
                                            __bf16* __restrict__ kb,
                                            __bf16* __restrict__ vtb) {
  __shared__ __bf16 sA[4 * 8192];
  __shared__ __bf16 sB[4 * 8192];
  const int raw = blockIdx.x;
  const int wid = (raw & 7) * 24 + (raw >> 3);   // nwg=192, bijective
  const int z = wid >> 6;
  const int r2 = wid & 63;
  const int tid = threadIdx.x;
  const __bf16* A;
  const __bf16* B;
  long row0, col0;
  if (z == 2) {            // A = Wv [1024][1024], B = x [4096][1024]
    A = wv; B = xb;
    row0 = (long)(r2 >> 4) * 256;   // feature tile (4)
    col0 = (long)(r2 & 15) * 256;   // token tile (16)
  } else {                 // A = x, B = Wq/Wk
    A = xb; B = (z == 0) ? wq : wk;
    row0 = (long)(r2 >> 2) * 256;   // token tile (16)
    col0 = (long)(r2 & 3) * 256;    // feature tile (4)
  }
  const long lda = 1024, ldb = 1024;
  f32x4 acc[8][4] = {};
  g8_loop(A, lda, row0, B, ldb, col0, 0, sA, sB, acc, tid);

  const int lane = tid & 63, w = tid >> 6;
  const int wr = w >> 2, wc = w & 3;
  const int lo = lane & 15, hi = lane >> 4;
#pragma unroll
  for (int m = 0; m < 8; ++m)
#pragma unroll
    for (int n = 0; n < 4; ++n)
#pragma unroll
      for (int i = 0; i < 4; ++i) {
        long r = row0 + wr * 128 + m * 16 + hi * 4 + i;
        long c = col0 + wc * 64 + n * 16 + lo;
        __bf16 v = (__bf16)acc[m][n][i];
        if (z == 0)      qb[r * 1024 + c] = v;
        else if (z == 1) kb[r * 1024 + c] = v;
        else             vtb[r * 4096 + c] = v;  // r=feature, c=token: coalesced
      }
}

__global__ __launch_bounds__(512) void qk8(const __bf16* __restrict__ qb,
                                           const __bf16* __restrict__ kb,
                                           __bf16* __restrict__ sim) {
  __shared__ __bf16 sA[4 * 8192];
  __shared__ __bf16 sB[4 * 8192];
  const int raw = blockIdx.x;
  const int wid = (raw & 7) * 32 + (raw >> 3);   // nwg=256, bijective
  const long row0 = (long)(wid >> 4) * 256;
  const long col0 = (long)(wid & 15) * 256;
  const int tid = threadIdx.x;
  const __bf16* A = qb;
  const __bf16* B = kb;
  const long lda = 1024, ldb = 1024;
  f32x4 acc[8][4] = {};
  g8_loop(A, lda, row0, B, ldb, col0, 0, sA, sB, acc, tid);

  const int lane = tid & 63, w = tid >> 6;
  const int wr = w >> 2, wc = w & 3;
  const int lo = lane & 15, hi = lane >> 4;
#pragma unroll
  for (int m = 0; m < 8; ++m)
#pragma unroll
    for (int n = 0; n < 4; ++n)
#pragma unroll
      for (int i = 0; i < 4; ++i) {
        long r = row0 + wr * 128 + m * 16 + hi * 4 + i;
        long c = col0 + wc * 64 + n * 16 + lo;
        sim[r * 4096 + c] = (__bf16)acc[m][n][i];
      }
}

// PV split-K x4: z -> K-tile window [z*32, z*32+32). z=0 -> out, else p[z].
__global__ __launch_bounds__(512) void pv8(const __bf16* __restrict__ attn,
                                           const __bf16* __restrict__ vt,
                                           float* __restrict__ out,
                                           float* __restrict__ p1,
                                           float* __restrict__ p2,
                                           float* __restrict__ p3) {
  __shared__ __bf16 sA[4 * 8192];
  __shared__ __bf16 sB[4 * 8192];
  const int raw = blockIdx.x;
  const int wid = (raw & 7) * 32 + (raw >> 3);   // nwg=256, bijective
  const int z = wid >> 6;
  const int r2 = wid & 63;
  const long row0 = (long)(r2 >> 2) * 256;       // token tile (16)
  const long col0 = (long)(r2 & 3) * 256;        // feature tile (4)
  float* C = (z == 0) ? out : (z == 1) ? p1 : (z == 2) ? p2 : p3;
  const int tid = threadIdx.x;
  const __bf16* A = attn;
  const __bf16* B = vt;
  const long lda = 4096, ldb = 4096;
  f32x4 acc[8][4] = {};
  g8_loop(A, lda, row0, B, ldb, col0, z * 32, sA, sB, acc, tid);

  const int lane = tid & 63, w = tid >> 6;
  const int wr = w >> 2, wc = w & 3;
  const int lo = lane & 15, hi = lane >> 4;
#pragma unroll
  for (int m = 0; m < 8; ++m)
#pragma unroll
    for (int n = 0; n < 4; ++n)
#pragma unroll
      for (int i = 0; i < 4; ++i) {
        long r = row0 + wr * 128 + m * 16 + hi * 4 + i;
        long c = col0 + wc * 64 + n * 16 + lo;
        C[r * 1024 + c] = acc[m][n][i];
      }
}

__global__ __launch_bounds__(256) void reduce_add4(float* __restrict__ out,
                                                   const float* __restrict__ a,
                                                   const float* __restrict__ b,
                                                   const float* __restrict__ c) {
  int i = blockIdx.x * 256 + threadIdx.x;  // 1,048,576 float4s
  float4 o = ((const float4*)out)[i];
  float4 x = ((const float4*)a)[i];
  float4 y = ((const float4*)b)[i];
  float4 z = ((const float4*)c)[i];
  o.x += x.x + y.x + z.x; o.y += x.y + y.y + z.y;
  o.z += x.z + y.z + z.z; o.w += x.w + y.w + z.w;
  ((float4*)out)[i] = o;
}

// One launch converts x, Wq, Wk, Wv to bf16. Blocks partitioned by range.
__global__ __launch_bounds__(256) void cvt_all(const float* __restrict__ x,
                                               const float* __restrict__ wq,
                                               const float* __restrict__ wk,
                                               const float* __restrict__ wv,
                                               __bf16* __restrict__ xb,
                                               __bf16* __restrict__ wqb,
                                               __bf16* __restrict__ wkb,
                                               __bf16* __restrict__ wvb) {
  int b = blockIdx.x;
  const float* in;
  __bf16* out;
  int base;
  if (b < 4096)      { in = x;  out = xb;  base = b; }
  else if (b < 5120) { in = wq; out = wqb; base = b - 4096; }
  else if (b < 6144) { in = wk; out = wkb; base = b - 5120; }
  else               { in = wv; out = wvb; base = b - 6144; }
  int i = base * 256 + threadIdx.x;
  float4 f = ((const float4*)in)[i];
  bf16x4 o;
  o[0] = (__bf16)f.x; o[1] = (__bf16)f.y; o[2] = (__bf16)f.z; o[3] = (__bf16)f.w;
  ((bf16x4*)out)[i] = o;
}

// One block per row of bf16 sim (ld 4096): mask (-1e20 where mask==0), stable
// softmax of row/32, write attn bf16 IN-PLACE.
__global__ __launch_bounds__(256) void softmax_rows(__bf16* __restrict__ sim,
                                                    const int* __restrict__ mask) {
  const int row = blockIdx.x;
  __bf16* rp = sim + (size_t)row * 4096;
  const int4* mrow = (const int4*)(mask + (size_t)row * 4096);
  const int tid = threadIdx.x;

  float vals[16];
  float lmax = -INFINITY;
#pragma unroll
  for (int j = 0; j < 2; ++j) {
    bf16x8 s = ((const bf16x8*)rp)[tid + 256 * j];
    int4 m0 = mrow[(tid + 256 * j) * 2];
    int4 m1 = mrow[(tid + 256 * j) * 2 + 1];
    float f[8];
#pragma unroll
    for (int e = 0; e < 8; ++e) f[e] = (float)s[e];
    f[0] = m0.x ? f[0] : -1e20f;  f[1] = m0.y ? f[1] : -1e20f;
    f[2] = m0.z ? f[2] : -1e20f;  f[3] = m0.w ? f[3] : -1e20f;
    f[4] = m1.x ? f[4] : -1e20f;  f[5] = m1.y ? f[5] : -1e20f;
    f[6] = m1.z ? f[6] : -1e20f;  f[7] = m1.w ? f[7] : -1e20f;
#pragma unroll
    for (int e = 0; e < 8; ++e) {
      vals[8 * j + e] = f[e];
      lmax = fmaxf(lmax, f[e]);
    }
  }
#pragma unroll
  for (int off = 32; off; off >>= 1) lmax = fmaxf(lmax, __shfl_xor(lmax, off));
  __shared__ float red[4];
  __shared__ float bro[2];
  if ((tid & 63) == 0) red[tid >> 6] = lmax;
  __syncthreads();
  if (tid == 0) bro[0] = fmaxf(fmaxf(red[0], red[1]), fmaxf(red[2], red[3]));
  __syncthreads();
  const float m = bro[0];

  float e[16];
  float lsum = 0.f;
#pragma unroll
  for (int j = 0; j < 16; ++j) {
    e[j] = __expf((vals[j] - m) * 0.03125f);  // /sqrt(1024)
    lsum += e[j];
  }
#pragma unroll
  for (int off = 32; off; off >>= 1) lsum += __shfl_xor(lsum, off);
  if ((tid & 63) == 0) red[tid >> 6] = lsum;
  __syncthreads();
  if (tid == 0) bro[1] = red[0] + red[1] + red[2] + red[3];
  __syncthreads();
  const float inv = 1.0f / bro[1];

#pragma unroll
  for (int j = 0; j < 2; ++j) {
    bf16x8 o;
#pragma unroll
    for (int q = 0; q < 8; ++q) o[q] = (__bf16)(e[8 * j + q] * inv);
    ((bf16x8*)rp)[tid + 256 * j] = o;
  }
}

extern "C" void kernel_launch(void* const* d_in, const int* in_sizes, int n_in,
                              void* d_out, int out_size, void* d_ws, size_t ws_size,
                              hipStream_t stream) {
  const float* x = (const float*)d_in[0];
  const int* mask = (const int*)d_in[1];
  const float* Wq = (const float*)d_in[2];
  const float* Wk = (const float*)d_in[3];
  const float* Wv = (const float*)d_in[4];
  float* out = (float*)d_out;

  // Workspace layout (102 MB):
  // [0,8M)   vT bf16    [8,16M)  x bf16
  // [16,18M) Wq bf16    [18,20M) Wk bf16   [20,22M) Wv bf16
  // [22,30M) q bf16     [30,38M) k bf16
  // [38,70M) sim bf16 (attn in-place, ld 4096)
  // PV-time (x,W,q,k dead): p1 [8,24M), p2 [70,86M), p3 [86,102M)
  char* ws = (char*)d_ws;
  __bf16* vtb = (__bf16*)(ws);
  __bf16* xb  = (__bf16*)(ws + (8ull << 20));
  __bf16* wqb = (__bf16*)(ws + (16ull << 20));
  __bf16* wkb = (__bf16*)(ws + (18ull << 20));
  __bf16* wvb = (__bf16*)(ws + (20ull << 20));
  __bf16* qb  = (__bf16*)(ws + (22ull << 20));
  __bf16* kb  = (__bf16*)(ws + (30ull << 20));
  __bf16* sim = (__bf16*)(ws + (38ull << 20));
  float*  p1  = (float*)(ws + (8ull << 20));
  float*  p2  = (float*)(ws + (70ull << 20));
  float*  p3  = (float*)(ws + (86ull << 20));

  cvt_all<<<7168, 256, 0, stream>>>(x, Wq, Wk, Wv, xb, wqb, wkb, wvb);

  dim3 blk(512);
  // q, k, vT: 192 blocks of 256^2
  qkv8<<<192, blk, 0, stream>>>(xb, wqb, wkb, wvb, qb, kb, vtb);
  // sim = q k^T (4096x4096): 256 blocks
  qk8<<<256, blk, 0, stream>>>(qb, kb, sim);
  // masked softmax, attn bf16 in-place
  softmax_rows<<<4096, 256, 0, stream>>>(sim, mask);
  // out = attn vT^T, split-K x4: 256 blocks
  pv8<<<256, blk, 0, stream>>>(sim, vtb, out, p1, p2, p3);
  reduce_add4<<<4096, 256, 0, stream>>>(out, p1, p2, p3);
}

// Round 7
// 157.683 us; speedup vs baseline: 1.2473x; 1.0315x over previous
//
#include <hip/hip_runtime.h>
#include <hip/hip_bf16.h>
#include <math.h>

// SelfAttention: out = softmax(mask(q k^T)/32) v, q=xWq^T k=xWk^T v=xWv^T
// N=4096 tokens, E=1024. bf16 MFMA compute, fp32 accumulate.
// R7: softmax fused into qk8 epilogue (bounded logits -> exp w/o max-sub,
//     unnormalized attn + atomic rowsum; normalize in final reduce).
//     PV split-K x2 with BM=128/BN=256 (MR=4 loop variant).

typedef __attribute__((ext_vector_type(8))) __bf16 bf16x8;
typedef __attribute__((ext_vector_type(4))) __bf16 bf16x4;
typedef __attribute__((ext_vector_type(4))) float f32x4;

__device__ __forceinline__ void gload_lds16(const void* g, void* l) {
  __builtin_amdgcn_global_load_lds(
      (__attribute__((address_space(1))) void*)(g),
      (__attribute__((address_space(3))) void*)(l), 16, 0, 0);
}

#define WAITB(N) asm volatile("s_waitcnt vmcnt(" #N ")\ns_barrier" ::: "memory")

// Swizzled ds_read of one bf16x8 fragment at (row r, k-chunk hi).
#define LDS_FRAG(base, r) \
  *(const bf16x8*)((base) + (r) * 32 + (((hi) ^ ((r) & 3)) * 8))

#define MM16(mq, AF)                                                        \
  __builtin_amdgcn_s_setprio(1);                                            \
  _Pragma("unroll") for (int m = 0; m < 4; ++m)                             \
    _Pragma("unroll") for (int n = 0; n < 4; ++n)                           \
      acc[(mq) * 4 + m][n] = __builtin_amdgcn_mfma_f32_16x16x32_bf16(       \
          AF[m], bfr[n], acc[(mq) * 4 + m][n], 0, 0, 0);                    \
  __builtin_amdgcn_s_setprio(0);

// ---- BMx256 tile, BK=32, 8 waves (2M x 4N), 4-deep LDS pipeline ----
// MR = A-frags per wave (8 -> BM=256, 4 -> BM=128). NT = K-tiles.
// Per tile: A = BM x 32 bf16 (MR/4 loads/thread), B = 256 x 32 (2 loads/thread).
// Swizzle: physical chunk c of row r holds logical k-chunk c^(r&3).
template <int MR, int NT>
__device__ __forceinline__ void g8_loop(const __bf16* __restrict__ A, long lda, long row0,
                                        const __bf16* __restrict__ B, long ldb, long col0,
                                        int kt0, __bf16* sA, __bf16* sB,
                                        f32x4 (&acc)[MR][4], int tid) {
  const int lane = tid & 63;
  const int w = tid >> 6;
  const int wr = w >> 2, wc = w & 3;
  const int lo = lane & 15, hi = lane >> 4;
  constexpr int ATILE = MR * 1024;   // LDS elems per A K-tile
  constexpr int AL = MR / 4;         // A staging loads per thread

  auto stageA = [&](int buf, int kt) {
#pragma unroll
    for (int j = 0; j < AL; ++j) {
      int p = tid + j * 512;
      int row = p >> 2, cg = (p & 3) ^ (row & 3);
      gload_lds16(A + (row0 + row) * lda + kt * 32 + cg * 8,
                  sA + buf * ATILE + p * 8);
    }
  };
  auto stageB = [&](int buf, int kt) {
#pragma unroll
    for (int j = 0; j < 2; ++j) {
      int p = tid + j * 512;
      int row = p >> 2, cg = (p & 3) ^ (row & 3);
      gload_lds16(B + (col0 + row) * ldb + kt * 32 + cg * 8,
                  sB + buf * 8192 + p * 8);
    }
  };

  // Prologue: stage tiles 0,1,2.
#pragma unroll
  for (int t = 0; t < 3; ++t) { stageA(t, kt0 + t); stageB(t, kt0 + t); }
  if constexpr (MR == 8) { WAITB(8); } else { WAITB(6); }  // tile0 landed

  for (int t = 0; t < NT; ++t) {
    const int d = t & 3;
    const __bf16* sAc = sA + d * ATILE;
    const __bf16* sBc = sB + d * 8192;
    const int s = (t + 3) & 3;   // stage target (free by construction)
    bf16x8 af[4], bfr[4];
#pragma unroll
    for (int m = 0; m < 4; ++m) af[m] = LDS_FRAG(sAc, wr * (MR * 16) + m * 16 + lo);
#pragma unroll
    for (int n = 0; n < 4; ++n) bfr[n] = LDS_FRAG(sBc, wc * 64 + n * 16 + lo);
    if (t + 3 < NT) stageA(s, kt0 + t + 3);
    if (MR == 4 && t + 3 < NT) stageB(s, kt0 + t + 3);
    __builtin_amdgcn_s_barrier();
    MM16(0, af);
    if constexpr (MR == 8) {
      __builtin_amdgcn_s_barrier();
      bf16x8 af2[4];
#pragma unroll
      for (int m = 0; m < 4; ++m) af2[m] = LDS_FRAG(sAc, wr * 128 + 64 + m * 16 + lo);
      if (t + 3 < NT) stageB(s, kt0 + t + 3);
      __builtin_amdgcn_s_barrier();
      MM16(1, af2);
    }
    // tile-end: ensure t+1 landed; keep later tiles' loads in flight.
    if (t + 3 < NT)      { if constexpr (MR == 8) { WAITB(8); } else { WAITB(6); } }
    else if (t + 2 < NT) { if constexpr (MR == 8) { WAITB(4); } else { WAITB(3); } }
    else                 { WAITB(0); }
  }
}

// ---------------- kernels ----------------

// Fused QKV. z=0: q = x Wq^T; z=1: k = x Wk^T; z=2: vT = Wv x^T (operands
// swapped so the C-write is coalesced).
__global__ __launch_bounds__(512) void qkv8(const __bf16* __restrict__ xb,
                                            const __bf16* __restrict__ wq,
                                            const __bf16* __restrict__ wk,
                                            const __bf16* __restrict__ wv,
                                            __bf16* __restrict__ qb,
                                            __bf16* __restrict__ kb,
                                            __bf16* __restrict__ vtb) {
  __shared__ __bf16 sA[4 * 8192];
  __shared__ __bf16 sB[4 * 8192];
  const int raw = blockIdx.x;
  const int wid = (raw & 7) * 24 + (raw >> 3);   // nwg=192, bijective
  const int z = wid >> 6;
  const int r2 = wid & 63;
  const int tid = threadIdx.x;
  const __bf16* A;
  const __bf16* B;
  long row0, col0;
  if (z == 2) {            // A = Wv [1024][1024], B = x [4096][1024]
    A = wv; B = xb;
    row0 = (long)(r2 >> 4) * 256;   // feature tile (4)
    col0 = (long)(r2 & 15) * 256;   // token tile (16)
  } else {                 // A = x, B = Wq/Wk
    A = xb; B = (z == 0) ? wq : wk;
    row0 = (long)(r2 >> 2) * 256;   // token tile (16)
    col0 = (long)(r2 & 3) * 256;    // feature tile (4)
  }
  f32x4 acc[8][4] = {};
  g8_loop<8, 32>(A, 1024, row0, B, 1024, col0, 0, sA, sB, acc, tid);

  const int lane = tid & 63, w = tid >> 6;
  const int wr = w >> 2, wc = w & 3;
  const int lo = lane & 15, hi = lane >> 4;
#pragma unroll
  for (int m = 0; m < 8; ++m)
#pragma unroll
    for (int n = 0; n < 4; ++n)
#pragma unroll
      for (int i = 0; i < 4; ++i) {
        long r = row0 + wr * 128 + m * 16 + hi * 4 + i;
        long c = col0 + wc * 64 + n * 16 + lo;
        __bf16 v = (__bf16)acc[m][n][i];
        if (z == 0)      qb[r * 1024 + c] = v;
        else if (z == 1) kb[r * 1024 + c] = v;
        else             vtb[r * 4096 + c] = v;  // r=feature, c=token: coalesced
      }
}

// sim tile + fused mask/exp epilogue: attn[r][c] = mask ? exp(sim/32) : 0
// (UNNORMALIZED; bounded logits make exp w/o max-sub fp32-safe), and
// rowsum[r] += partial row sums (device-scope atomics).
__global__ __launch_bounds__(512) void qk8(const __bf16* __restrict__ qb,
                                           const __bf16* __restrict__ kb,
                                           const int* __restrict__ mask,
                                           __bf16* __restrict__ attn,
                                           float* __restrict__ rowsum) {
  __shared__ __bf16 sA[4 * 8192];
  __shared__ __bf16 sB[4 * 8192];
  const int raw = blockIdx.x;
  const int wid = (raw & 7) * 32 + (raw >> 3);   // nwg=256, bijective
  const long row0 = (long)(wid >> 4) * 256;
  const long col0 = (long)(wid & 15) * 256;
  const int tid = threadIdx.x;
  f32x4 acc[8][4] = {};
  g8_loop<8, 32>(qb, 1024, row0, kb, 1024, col0, 0, sA, sB, acc, tid);

  const int lane = tid & 63, w = tid >> 6;
  const int wr = w >> 2, wc = w & 3;
  const int lo = lane & 15, hi = lane >> 4;
#pragma unroll
  for (int m = 0; m < 8; ++m)
#pragma unroll
    for (int i = 0; i < 4; ++i) {
      long r = row0 + wr * 128 + m * 16 + hi * 4 + i;
      float s = 0.f;
#pragma unroll
      for (int n = 0; n < 4; ++n) {
        long c = col0 + wc * 64 + n * 16 + lo;
        int mk = mask[r * 4096 + c];
        float p = mk ? __expf(acc[m][n][i] * 0.03125f) : 0.f;
        attn[r * 4096 + c] = (__bf16)p;
        s += p;
      }
      // sum across the 16 lo-lanes (same r for fixed hi)
      s += __shfl_xor(s, 1); s += __shfl_xor(s, 2);
      s += __shfl_xor(s, 4); s += __shfl_xor(s, 8);
      if (lo == 0) atomicAdd(&rowsum[r], s);
    }
}

// PV split-K x2, BM=128 BN=256: z -> K-tile window [z*64, z*64+64).
// z=0 -> out, z=1 -> p1. Grid 256 blocks (32 row x 4 col x 2 z).
__global__ __launch_bounds__(512) void pv8(const __bf16* __restrict__ attn,
                                           const __bf16* __restrict__ vt,
                                           float* __restrict__ out,
                                           float* __restrict__ p1) {
  __shared__ __bf16 sA[4 * 4096];
  __shared__ __bf16 sB[4 * 8192];
  const int raw = blockIdx.x;
  const int wid = (raw & 7) * 32 + (raw >> 3);   // nwg=256, bijective
  const int z = wid >> 7;
  const int r2 = wid & 127;
  const long row0 = (long)(r2 >> 2) * 128;       // token tile (32)
  const long col0 = (long)(r2 & 3) * 256;        // feature tile (4)
  float* C = z ? p1 : out;
  const int tid = threadIdx.x;
  f32x4 acc[4][4] = {};
  g8_loop<4, 64>(attn, 4096, row0, vt, 4096, col0, z * 64, sA, sB, acc, tid);

  const int lane = tid & 63, w = tid >> 6;
  const int wr = w >> 2, wc = w & 3;
  const int lo = lane & 15, hi = lane >> 4;
#pragma unroll
  for (int m = 0; m < 4; ++m)
#pragma unroll
    for (int n = 0; n < 4; ++n)
#pragma unroll
      for (int i = 0; i < 4; ++i) {
        long r = row0 + wr * 64 + m * 16 + hi * 4 + i;
        long c = col0 + wc * 64 + n * 16 + lo;
        C[r * 1024 + c] = acc[m][n][i];
      }
}

// out = (out + p1) / rowsum[row]  (normalization folded in here)
__global__ __launch_bounds__(256) void reduce_add2(float* __restrict__ out,
                                                   const float* __restrict__ p1,
                                                   const float* __restrict__ rs) {
  int i = blockIdx.x * 256 + threadIdx.x;  // 1,048,576 float4s over [4096][1024]
  int row = i >> 8;                        // (i*4) / 1024
  float inv = 1.0f / rs[row];
  float4 a = ((const float4*)out)[i];
  float4 b = ((const float4*)p1)[i];
  a.x = (a.x + b.x) * inv; a.y = (a.y + b.y) * inv;
  a.z = (a.z + b.z) * inv; a.w = (a.w + b.w) * inv;
  ((float4*)out)[i] = a;
}

// Converts x, Wq, Wk, Wv to bf16; last block zeroes rowsum.
__global__ __launch_bounds__(256) void cvt_all(const float* __restrict__ x,
                                               const float* __restrict__ wq,
                                               const float* __restrict__ wk,
                                               const float* __restrict__ wv,
                                               __bf16* __restrict__ xb,
                                               __bf16* __restrict__ wqb,
                                               __bf16* __restrict__ wkb,
                                               __bf16* __restrict__ wvb,
                                               float* __restrict__ rowsum) {
  int b = blockIdx.x;
  if (b >= 7168) {  // zero rowsum[4096]
#pragma unroll
    for (int j = 0; j < 16; ++j) rowsum[threadIdx.x * 16 + j] = 0.f;
    return;
  }
  const float* in;
  __bf16* out;
  int base;
  if (b < 4096)      { in = x;  out = xb;  base = b; }
  else if (b < 5120) { in = wq; out = wqb; base = b - 4096; }
  else if (b < 6144) { in = wk; out = wkb; base = b - 5120; }
  else               { in = wv; out = wvb; base = b - 6144; }
  int i = base * 256 + threadIdx.x;
  float4 f = ((const float4*)in)[i];
  bf16x4 o;
  o[0] = (__bf16)f.x; o[1] = (__bf16)f.y; o[2] = (__bf16)f.z; o[3] = (__bf16)f.w;
  ((bf16x4*)out)[i] = o;
}

extern "C" void kernel_launch(void* const* d_in, const int* in_sizes, int n_in,
                              void* d_out, int out_size, void* d_ws, size_t ws_size,
                              hipStream_t stream) {
  const float* x = (const float*)d_in[0];
  const int* mask = (const int*)d_in[1];
  const float* Wq = (const float*)d_in[2];
  const float* Wk = (const float*)d_in[3];
  const float* Wv = (const float*)d_in[4];
  float* out = (float*)d_out;

  // Workspace layout (<= 71 MB):
  // [0,8M)   vT bf16    [8,16M)  x bf16
  // [16,18M) Wq bf16    [18,20M) Wk bf16   [20,22M) Wv bf16
  // [22,30M) q bf16     [30,38M) k bf16
  // [38,70M) attn bf16 (unnormalized, ld 4096)
  // [70M, +16KB) rowsum fp32
  // PV-time (x,W,q,k dead): p1 [8,24M)
  char* ws = (char*)d_ws;
  __bf16* vtb = (__bf16*)(ws);
  __bf16* xb  = (__bf16*)(ws + (8ull << 20));
  __bf16* wqb = (__bf16*)(ws + (16ull << 20));
  __bf16* wkb = (__bf16*)(ws + (18ull << 20));
  __bf16* wvb = (__bf16*)(ws + (20ull << 20));
  __bf16* qb  = (__bf16*)(ws + (22ull << 20));
  __bf16* kb  = (__bf16*)(ws + (30ull << 20));
  __bf16* attn = (__bf16*)(ws + (38ull << 20));
  float*  rowsum = (float*)(ws + (70ull << 20));
  float*  p1  = (float*)(ws + (8ull << 20));

  cvt_all<<<7169, 256, 0, stream>>>(x, Wq, Wk, Wv, xb, wqb, wkb, wvb, rowsum);

  dim3 blk(512);
  // q, k, vT: 192 blocks of 256^2
  qkv8<<<192, blk, 0, stream>>>(xb, wqb, wkb, wvb, qb, kb, vtb);
  // attn = mask ? exp(q k^T / 32) : 0 (unnormalized) + rowsum atomics
  qk8<<<256, blk, 0, stream>>>(qb, kb, mask, attn, rowsum);
  // out_partial = attn vT^T, split-K x2
  pv8<<<256, blk, 0, stream>>>(attn, vtb, out, p1);
  // out = (out + p1) / rowsum
  reduce_add2<<<4096, 256, 0, stream>>>(out, p1, rowsum);
}

// Round 8
// 157.659 us; speedup vs baseline: 1.2474x; 1.0001x over previous
//
#include <hip/hip_runtime.h>
#include <hip/hip_bf16.h>
#include <math.h>

// SelfAttention: out = softmax(mask(q k^T)/32) v, q=xWq^T k=xWk^T v=xWv^T
// N=4096 tokens, E=1024. bf16 MFMA compute, fp32 accumulate.
// R8: conflict-free BK=32 swizzle ((row>>1)&3 -> 8 balanced bank windows);
//     qk8 epilogue through LDS transpose -> coalesced mask/attn/rowsum.

typedef __attribute__((ext_vector_type(8))) __bf16 bf16x8;
typedef __attribute__((ext_vector_type(4))) __bf16 bf16x4;
typedef __attribute__((ext_vector_type(4))) float f32x4;

__device__ __forceinline__ void gload_lds16(const void* g, void* l) {
  __builtin_amdgcn_global_load_lds(
      (__attribute__((address_space(1))) void*)(g),
      (__attribute__((address_space(3))) void*)(l), 16, 0, 0);
}

#define WAITB(N) asm volatile("s_waitcnt vmcnt(" #N ")\ns_barrier" ::: "memory")

// Swizzled ds_read of one bf16x8 fragment at (row r, k-chunk hi).
// Window = 4*(r&1) + (hi ^ ((r>>1)&3)): 8 balanced 4-bank windows per
// 16-lane group -> 2 lanes/window (free, m136).
#define LDS_FRAG(base, r) \
  *(const bf16x8*)((base) + (r) * 32 + (((hi) ^ (((r) >> 1) & 3)) * 8))

#define MM16(mq, AF)                                                        \
  __builtin_amdgcn_s_setprio(1);                                            \
  _Pragma("unroll") for (int m = 0; m < 4; ++m)                             \
    _Pragma("unroll") for (int n = 0; n < 4; ++n)                           \
      acc[(mq) * 4 + m][n] = __builtin_amdgcn_mfma_f32_16x16x32_bf16(       \
          AF[m], bfr[n], acc[(mq) * 4 + m][n], 0, 0, 0);                    \
  __builtin_amdgcn_s_setprio(0);

// ---- BMx256 tile, BK=32, 8 waves (2M x 4N), 4-deep LDS pipeline ----
// MR = A-frags per wave (8 -> BM=256, 4 -> BM=128). NT = K-tiles.
template <int MR, int NT>
__device__ __forceinline__ void g8_loop(const __bf16* __restrict__ A, long lda, long row0,
                                        const __bf16* __restrict__ B, long ldb, long col0,
                                        int kt0, __bf16* sA, __bf16* sB,
                                        f32x4 (&acc)[MR][4], int tid) {
  const int lane = tid & 63;
  const int w = tid >> 6;
  const int wr = w >> 2, wc = w & 3;
  const int lo = lane & 15, hi = lane >> 4;
  constexpr int ATILE = MR * 1024;   // LDS elems per A K-tile
  constexpr int AL = MR / 4;         // A staging loads per thread

  auto stageA = [&](int buf, int kt) {
#pragma unroll
    for (int j = 0; j < AL; ++j) {
      int p = tid + j * 512;
      int row = p >> 2, cg = (p & 3) ^ ((row >> 1) & 3);
      gload_lds16(A + (row0 + row) * lda + kt * 32 + cg * 8,
                  sA + buf * ATILE + p * 8);
    }
  };
  auto stageB = [&](int buf, int kt) {
#pragma unroll
    for (int j = 0; j < 2; ++j) {
      int p = tid + j * 512;
      int row = p >> 2, cg = (p & 3) ^ ((row >> 1) & 3);
      gload_lds16(B + (col0 + row) * ldb + kt * 32 + cg * 8,
                  sB + buf * 8192 + p * 8);
    }
  };

  // Prologue: stage tiles 0,1,2.
#pragma unroll
  for (int t = 0; t < 3; ++t) { stageA(t, kt0 + t); stageB(t, kt0 + t); }
  if constexpr (MR == 8) { WAITB(8); } else { WAITB(6); }  // tile0 landed

  for (int t = 0; t < NT; ++t) {
    const int d = t & 3;
    const __bf16* sAc = sA + d * ATILE;
    const __bf16* sBc = sB + d * 8192;
    const int s = (t + 3) & 3;   // stage target (free by construction)
    bf16x8 af[4], bfr[4];
#pragma unroll
    for (int m = 0; m < 4; ++m) af[m] = LDS_FRAG(sAc, wr * (MR * 16) + m * 16 + lo);
#pragma unroll
    for (int n = 0; n < 4; ++n) bfr[n] = LDS_FRAG(sBc, wc * 64 + n * 16 + lo);
    if (t + 3 < NT) stageA(s, kt0 + t + 3);
    if (MR == 4 && t + 3 < NT) stageB(s, kt0 + t + 3);
    __builtin_amdgcn_s_barrier();
    MM16(0, af);
    if constexpr (MR == 8) {
      __builtin_amdgcn_s_barrier();
      bf16x8 af2[4];
#pragma unroll
      for (int m = 0; m < 4; ++m) af2[m] = LDS_FRAG(sAc, wr * 128 + 64 + m * 16 + lo);
      if (t + 3 < NT) stageB(s, kt0 + t + 3);
      __builtin_amdgcn_s_barrier();
      MM16(1, af2);
    }
    // tile-end: ensure t+1 landed; keep later tiles' loads in flight.
    if (t + 3 < NT)      { if constexpr (MR == 8) { WAITB(8); } else { WAITB(6); } }
    else if (t + 2 < NT) { if constexpr (MR == 8) { WAITB(4); } else { WAITB(3); } }
    else                 { WAITB(0); }
  }
}

// ---------------- kernels ----------------

// Fused QKV. z=0: q = x Wq^T; z=1: k = x Wk^T; z=2: vT = Wv x^T (operands
// swapped so the C-write is coalesced).
__global__ __launch_bounds__(512) void qkv8(const __bf16* __restrict__ xb,
                                            const __bf16* __restrict__ wq,
                                            const __bf16* __restrict__ wk,
                                            const __bf16* __restrict__ wv,
                                            __bf16* __restrict__ qb,
                                            __bf16* __restrict__ kb,
                                            __bf16* __restrict__ vtb) {
  __shared__ __bf16 sA[4 * 8192];
  __shared__ __bf16 sB[4 * 8192];
  const int raw = blockIdx.x;
  const int wid = (raw & 7) * 24 + (raw >> 3);   // nwg=192, bijective
  const int z = wid >> 6;
  const int r2 = wid & 63;
  const int tid = threadIdx.x;
  const __bf16* A;
  const __bf16* B;
  long row0, col0;
  if (z == 2) {            // A = Wv [1024][1024], B = x [4096][1024]
    A = wv; B = xb;
    row0 = (long)(r2 >> 4) * 256;   // feature tile (4)
    col0 = (long)(r2 & 15) * 256;   // token tile (16)
  } else {                 // A = x, B = Wq/Wk
    A = xb; B = (z == 0) ? wq : wk;
    row0 = (long)(r2 >> 2) * 256;   // token tile (16)
    col0 = (long)(r2 & 3) * 256;    // feature tile (4)
  }
  f32x4 acc[8][4] = {};
  g8_loop<8, 32>(A, 1024, row0, B, 1024, col0, 0, sA, sB, acc, tid);

  const int lane = tid & 63, w = tid >> 6;
  const int wr = w >> 2, wc = w & 3;
  const int lo = lane & 15, hi = lane >> 4;
#pragma unroll
  for (int m = 0; m < 8; ++m)
#pragma unroll
    for (int n = 0; n < 4; ++n)
#pragma unroll
      for (int i = 0; i < 4; ++i) {
        long r = row0 + wr * 128 + m * 16 + hi * 4 + i;
        long c = col0 + wc * 64 + n * 16 + lo;
        __bf16 v = (__bf16)acc[m][n][i];
        if (z == 0)      qb[r * 1024 + c] = v;
        else if (z == 1) kb[r * 1024 + c] = v;
        else             vtb[r * 4096 + c] = v;  // r=feature, c=token: coalesced
      }
}

// sim tile + fused mask/exp epilogue via LDS transpose.
// attn[r][c] = mask ? exp(sim/32) : 0 (UNNORMALIZED; bounded logits),
// rowsum[r] += partial row sums (device-scope atomics).
__global__ __launch_bounds__(512) void qk8(const __bf16* __restrict__ qb,
                                           const __bf16* __restrict__ kb,
                                           const int* __restrict__ mask,
                                           __bf16* __restrict__ attn,
                                           float* __restrict__ rowsum) {
  __shared__ __bf16 smem[65536];   // loop: sA=smem[0:32768), sB=[32768:65536)
  const int raw = blockIdx.x;
  const int wid = (raw & 7) * 32 + (raw >> 3);   // nwg=256, bijective
  const long row0 = (long)(wid >> 4) * 256;
  const long col0 = (long)(wid & 15) * 256;
  const int tid = threadIdx.x;
  f32x4 acc[8][4] = {};
  g8_loop<8, 32>(qb, 1024, row0, kb, 1024, col0, 0, smem, smem + 32768, acc, tid);

  const int lane = tid & 63, w = tid >> 6;
  const int wr = w >> 2, wc = w & 3;
  const int lo = lane & 15, hi = lane >> 4;
  // Phase 1: park raw sim tile (bf16) in smem [256][256].
#pragma unroll
  for (int m = 0; m < 8; ++m)
#pragma unroll
    for (int n = 0; n < 4; ++n)
#pragma unroll
      for (int i = 0; i < 4; ++i)
        smem[(wr * 128 + m * 16 + hi * 4 + i) * 256 + wc * 64 + n * 16 + lo] =
            (__bf16)acc[m][n][i];
  __syncthreads();
  // Phase 2: each thread owns a contiguous 128-elem half-row: coalesced
  // int4 mask loads, exp, coalesced bf16x8 attn stores, rowsum reduce.
  const int rr = tid >> 1, hh = tid & 1;
  const long gr = row0 + rr;
  const long gc = col0 + hh * 128;
  const __bf16* srow = smem + rr * 256 + hh * 128;
  const int4* mrow = (const int4*)(mask + gr * 4096 + gc);
  __bf16* arow = attn + gr * 4096 + gc;
  float s = 0.f;
#pragma unroll
  for (int j = 0; j < 16; ++j) {
    bf16x8 v = ((const bf16x8*)srow)[j];
    int4 m0 = mrow[2 * j], m1 = mrow[2 * j + 1];
    float p[8];
    p[0] = m0.x ? __expf((float)v[0] * 0.03125f) : 0.f;
    p[1] = m0.y ? __expf((float)v[1] * 0.03125f) : 0.f;
    p[2] = m0.z ? __expf((float)v[2] * 0.03125f) : 0.f;
    p[3] = m0.w ? __expf((float)v[3] * 0.03125f) : 0.f;
    p[4] = m1.x ? __expf((float)v[4] * 0.03125f) : 0.f;
    p[5] = m1.y ? __expf((float)v[5] * 0.03125f) : 0.f;
    p[6] = m1.z ? __expf((float)v[6] * 0.03125f) : 0.f;
    p[7] = m1.w ? __expf((float)v[7] * 0.03125f) : 0.f;
    bf16x8 o;
#pragma unroll
    for (int e = 0; e < 8; ++e) { o[e] = (__bf16)p[e]; s += p[e]; }
    ((bf16x8*)arow)[j] = o;
  }
  s += __shfl_xor(s, 1);   // pair threads (rr, hh=0/1) share a wave
  if (hh == 0) atomicAdd(&rowsum[gr], s);
}

// PV split-K x2, BM=128 BN=256: z -> K-tile window [z*64, z*64+64).
// z=0 -> out, z=1 -> p1. Grid 256 blocks (32 row x 4 col x 2 z).
__global__ __launch_bounds__(512) void pv8(const __bf16* __restrict__ attn,
                                           const __bf16* __restrict__ vt,
                                           float* __restrict__ out,
                                           float* __restrict__ p1) {
  __shared__ __bf16 sA[4 * 4096];
  __shared__ __bf16 sB[4 * 8192];
  const int raw = blockIdx.x;
  const int wid = (raw & 7) * 32 + (raw >> 3);   // nwg=256, bijective
  const int z = wid >> 7;
  const int r2 = wid & 127;
  const long row0 = (long)(r2 >> 2) * 128;       // token tile (32)
  const long col0 = (long)(r2 & 3) * 256;        // feature tile (4)
  float* C = z ? p1 : out;
  const int tid = threadIdx.x;
  f32x4 acc[4][4] = {};
  g8_loop<4, 64>(attn, 4096, row0, vt, 4096, col0, z * 64, sA, sB, acc, tid);

  const int lane = tid & 63, w = tid >> 6;
  const int wr = w >> 2, wc = w & 3;
  const int lo = lane & 15, hi = lane >> 4;
#pragma unroll
  for (int m = 0; m < 4; ++m)
#pragma unroll
    for (int n = 0; n < 4; ++n)
#pragma unroll
      for (int i = 0; i < 4; ++i) {
        long r = row0 + wr * 64 + m * 16 + hi * 4 + i;
        long c = col0 + wc * 64 + n * 16 + lo;
        C[r * 1024 + c] = acc[m][n][i];
      }
}

// out = (out + p1) / rowsum[row]  (normalization folded in here)
__global__ __launch_bounds__(256) void reduce_add2(float* __restrict__ out,
                                                   const float* __restrict__ p1,
                                                   const float* __restrict__ rs) {
  int i = blockIdx.x * 256 + threadIdx.x;  // 1,048,576 float4s over [4096][1024]
  int row = i >> 8;                        // (i*4) / 1024
  float inv = 1.0f / rs[row];
  float4 a = ((const float4*)out)[i];
  float4 b = ((const float4*)p1)[i];
  a.x = (a.x + b.x) * inv; a.y = (a.y + b.y) * inv;
  a.z = (a.z + b.z) * inv; a.w = (a.w + b.w) * inv;
  ((float4*)out)[i] = a;
}

// Converts x, Wq, Wk, Wv to bf16; last block zeroes rowsum.
__global__ __launch_bounds__(256) void cvt_all(const float* __restrict__ x,
                                               const float* __restrict__ wq,
                                               const float* __restrict__ wk,
                                               const float* __restrict__ wv,
                                               __bf16* __restrict__ xb,
                                               __bf16* __restrict__ wqb,
                                               __bf16* __restrict__ wkb,
                                               __bf16* __restrict__ wvb,
                                               float* __restrict__ rowsum) {
  int b = blockIdx.x;
  if (b >= 7168) {  // zero rowsum[4096]
#pragma unroll
    for (int j = 0; j < 16; ++j) rowsum[threadIdx.x * 16 + j] = 0.f;
    return;
  }
  const float* in;
  __bf16* out;
  int base;
  if (b < 4096)      { in = x;  out = xb;  base = b; }
  else if (b < 5120) { in = wq; out = wqb; base = b - 4096; }
  else if (b < 6144) { in = wk; out = wkb; base = b - 5120; }
  else               { in = wv; out = wvb; base = b - 6144; }
  int i = base * 256 + threadIdx.x;
  float4 f = ((const float4*)in)[i];
  bf16x4 o;
  o[0] = (__bf16)f.x; o[1] = (__bf16)f.y; o[2] = (__bf16)f.z; o[3] = (__bf16)f.w;
  ((bf16x4*)out)[i] = o;
}

extern "C" void kernel_launch(void* const* d_in, const int* in_sizes, int n_in,
                              void* d_out, int out_size, void* d_ws, size_t ws_size,
                              hipStream_t stream) {
  const float* x = (const float*)d_in[0];
  const int* mask = (const int*)d_in[1];
  const float* Wq = (const float*)d_in[2];
  const float* Wk = (const float*)d_in[3];
  const float* Wv = (const float*)d_in[4];
  float* out = (float*)d_out;

  // Workspace layout (<= 71 MB):
  // [0,8M)   vT bf16    [8,16M)  x bf16
  // [16,18M) Wq bf16    [18,20M) Wk bf16   [20,22M) Wv bf16
  // [22,30M) q bf16     [30,38M) k bf16
  // [38,70M) attn bf16 (unnormalized, ld 4096)
  // [70M, +16KB) rowsum fp32
  // PV-time (x,W,q,k dead): p1 [8,24M)
  char* ws = (char*)d_ws;
  __bf16* vtb = (__bf16*)(ws);
  __bf16* xb  = (__bf16*)(ws + (8ull << 20));
  __bf16* wqb = (__bf16*)(ws + (16ull << 20));
  __bf16* wkb = (__bf16*)(ws + (18ull << 20));
  __bf16* wvb = (__bf16*)(ws + (20ull << 20));
  __bf16* qb  = (__bf16*)(ws + (22ull << 20));
  __bf16* kb  = (__bf16*)(ws + (30ull << 20));
  __bf16* attn = (__bf16*)(ws + (38ull << 20));
  float*  rowsum = (float*)(ws + (70ull << 20));
  float*  p1  = (float*)(ws + (8ull << 20));

  cvt_all<<<7169, 256, 0, stream>>>(x, Wq, Wk, Wv, xb, wqb, wkb, wvb, rowsum);

  dim3 blk(512);
  // q, k, vT: 192 blocks of 256^2
  qkv8<<<192, blk, 0, stream>>>(xb, wqb, wkb, wvb, qb, kb, vtb);
  // attn = mask ? exp(q k^T / 32) : 0 (unnormalized) + rowsum atomics
  qk8<<<256, blk, 0, stream>>>(qb, kb, mask, attn, rowsum);
  // out_partial = attn vT^T, split-K x2
  pv8<<<256, blk, 0, stream>>>(attn, vtb, out, p1);
  // out = (out + p1) / rowsum
  reduce_add2<<<4096, 256, 0, stream>>>(out, p1, rowsum);
}

// Round 9
// 155.402 us; speedup vs baseline: 1.2656x; 1.0145x over previous
//
#include <hip/hip_runtime.h>
#include <hip/hip_bf16.h>
#include <math.h>

// SelfAttention: out = softmax(mask(q k^T)/32) v, q=xWq^T k=xWk^T v=xWv^T
// N=4096 tokens, E=1024. bf16 MFMA compute, fp32 accumulate.
// R9: un-fused (separate BW-roofline softmax); qk8 pure GEMM w/ 2D XCD
//     panel tiling; pv4 = 4-wave 128x128 no-split PV (no partials/reduce).

typedef __attribute__((ext_vector_type(8))) __bf16 bf16x8;
typedef __attribute__((ext_vector_type(4))) __bf16 bf16x4;
typedef __attribute__((ext_vector_type(4))) float f32x4;

__device__ __forceinline__ void gload_lds16(const void* g, void* l) {
  __builtin_amdgcn_global_load_lds(
      (__attribute__((address_space(1))) void*)(g),
      (__attribute__((address_space(3))) void*)(l), 16, 0, 0);
}

#define WAITB(N) asm volatile("s_waitcnt vmcnt(" #N ")\ns_barrier" ::: "memory")

// Swizzled ds_read of one bf16x8 fragment at (row r, k-chunk hi).
#define LDS_FRAG(base, r) \
  *(const bf16x8*)((base) + (r) * 32 + (((hi) ^ (((r) >> 1) & 3)) * 8))

#define MM16(mq, AF)                                                        \
  __builtin_amdgcn_s_setprio(1);                                            \
  _Pragma("unroll") for (int m = 0; m < 4; ++m)                             \
    _Pragma("unroll") for (int n = 0; n < 4; ++n)                           \
      acc[(mq) * 4 + m][n] = __builtin_amdgcn_mfma_f32_16x16x32_bf16(       \
          AF[m], bfr[n], acc[(mq) * 4 + m][n], 0, 0, 0);                    \
  __builtin_amdgcn_s_setprio(0);

// ---- 256x256 tile, BK=32, 8 waves (2M x 4N), 4-deep LDS pipeline ----
template <int NT>
__device__ __forceinline__ void g8_loop(const __bf16* __restrict__ A, long lda, long row0,
                                        const __bf16* __restrict__ B, long ldb, long col0,
                                        int kt0, __bf16* sA, __bf16* sB,
                                        f32x4 (&acc)[8][4], int tid) {
  const int lane = tid & 63;
  const int w = tid >> 6;
  const int wr = w >> 2, wc = w & 3;
  const int lo = lane & 15, hi = lane >> 4;

  auto stageA = [&](int buf, int kt) {
#pragma unroll
    for (int j = 0; j < 2; ++j) {
      int p = tid + j * 512;
      int row = p >> 2, cg = (p & 3) ^ ((row >> 1) & 3);
      gload_lds16(A + (row0 + row) * lda + kt * 32 + cg * 8,
                  sA + buf * 8192 + p * 8);
    }
  };
  auto stageB = [&](int buf, int kt) {
#pragma unroll
    for (int j = 0; j < 2; ++j) {
      int p = tid + j * 512;
      int row = p >> 2, cg = (p & 3) ^ ((row >> 1) & 3);
      gload_lds16(B + (col0 + row) * ldb + kt * 32 + cg * 8,
                  sB + buf * 8192 + p * 8);
    }
  };

#pragma unroll
  for (int t = 0; t < 3; ++t) { stageA(t, kt0 + t); stageB(t, kt0 + t); }
  WAITB(8);  // tile0 landed; tiles 1,2 in flight

  for (int t = 0; t < NT; ++t) {
    const int d = t & 3;
    const __bf16* sAc = sA + d * 8192;
    const __bf16* sBc = sB + d * 8192;
    const int s = (t + 3) & 3;
    bf16x8 af[4], bfr[4];
#pragma unroll
    for (int m = 0; m < 4; ++m) af[m] = LDS_FRAG(sAc, wr * 128 + m * 16 + lo);
#pragma unroll
    for (int n = 0; n < 4; ++n) bfr[n] = LDS_FRAG(sBc, wc * 64 + n * 16 + lo);
    if (t + 3 < NT) stageA(s, kt0 + t + 3);
    __builtin_amdgcn_s_barrier();
    MM16(0, af);
    __builtin_amdgcn_s_barrier();
    bf16x8 af2[4];
#pragma unroll
    for (int m = 0; m < 4; ++m) af2[m] = LDS_FRAG(sAc, wr * 128 + 64 + m * 16 + lo);
    if (t + 3 < NT) stageB(s, kt0 + t + 3);
    __builtin_amdgcn_s_barrier();
    MM16(1, af2);
    if (t + 3 < NT)      { WAITB(8); }
    else if (t + 2 < NT) { WAITB(4); }
    else                 { WAITB(0); }
  }
}

// ---------------- kernels ----------------

// Fused QKV. z=0: q = x Wq^T; z=1: k = x Wk^T; z=2: vT = Wv x^T.
__global__ __launch_bounds__(512) void qkv8(const __bf16* __restrict__ xb,
                                            const __bf16* __restrict__ wq,
                                            const __bf16* __restrict__ wk,
                                            const __bf16* __restrict__ wv,
                                            __bf16* __restrict__ qb,
                                            __bf16* __restrict__ kb,
                                            __bf16* __restrict__ vtb) {
  __shared__ __bf16 sA[4 * 8192];
  __shared__ __bf16 sB[4 * 8192];
  const int raw = blockIdx.x;
  const int wid = (raw & 7) * 24 + (raw >> 3);   // nwg=192, bijective
  const int z = wid >> 6;
  const int r2 = wid & 63;
  const int tid = threadIdx.x;
  const __bf16* A;
  const __bf16* B;
  long row0, col0;
  if (z == 2) {            // A = Wv, B = x  -> vT coalesced
    A = wv; B = xb;
    row0 = (long)(r2 >> 4) * 256;
    col0 = (long)(r2 & 15) * 256;
  } else {
    A = xb; B = (z == 0) ? wq : wk;
    row0 = (long)(r2 >> 2) * 256;
    col0 = (long)(r2 & 3) * 256;
  }
  f32x4 acc[8][4] = {};
  g8_loop<32>(A, 1024, row0, B, 1024, col0, 0, sA, sB, acc, tid);

  const int lane = tid & 63, w = tid >> 6;
  const int wr = w >> 2, wc = w & 3;
  const int lo = lane & 15, hi = lane >> 4;
#pragma unroll
  for (int m = 0; m < 8; ++m)
#pragma unroll
    for (int n = 0; n < 4; ++n)
#pragma unroll
      for (int i = 0; i < 4; ++i) {
        long r = row0 + wr * 128 + m * 16 + hi * 4 + i;
        long c = col0 + wc * 64 + n * 16 + lo;
        __bf16 v = (__bf16)acc[m][n][i];
        if (z == 0)      qb[r * 1024 + c] = v;
        else if (z == 1) kb[r * 1024 + c] = v;
        else             vtb[r * 4096 + c] = v;
      }
}

// sim = q k^T (bf16 out, ld 4096). 2D XCD panel tiling: each XCD owns a
// 4x8 panel sub-grid -> L2 working set 6MB (vs 9MB for 1D).
__global__ __launch_bounds__(512) void qk8(const __bf16* __restrict__ qb,
                                           const __bf16* __restrict__ kb,
                                           __bf16* __restrict__ sim) {
  __shared__ __bf16 sA[4 * 8192];
  __shared__ __bf16 sB[4 * 8192];
  const int raw = blockIdx.x;
  const int xcd = raw & 7, idx = raw >> 3;       // nwg=256
  const int rp = (xcd >> 1) * 4 + (idx >> 3);    // [0,16)
  const int cp = (xcd & 1) * 8 + (idx & 7);      // [0,16)
  const long row0 = (long)rp * 256;
  const long col0 = (long)cp * 256;
  const int tid = threadIdx.x;
  f32x4 acc[8][4] = {};
  g8_loop<32>(qb, 1024, row0, kb, 1024, col0, 0, sA, sB, acc, tid);

  const int lane = tid & 63, w = tid >> 6;
  const int wr = w >> 2, wc = w & 3;
  const int lo = lane & 15, hi = lane >> 4;
#pragma unroll
  for (int m = 0; m < 8; ++m)
#pragma unroll
    for (int n = 0; n < 4; ++n)
#pragma unroll
      for (int i = 0; i < 4; ++i) {
        long r = row0 + wr * 128 + m * 16 + hi * 4 + i;
        long c = col0 + wc * 64 + n * 16 + lo;
        sim[r * 4096 + c] = (__bf16)acc[m][n][i];
      }
}

// PV, no split: 128x128 tile, 4 waves (2x2 of 64x64), BK=32, NT=128.
// Grid 256 = 32 row-panels x 8 col-panels; 64KB LDS -> 2 blocks/CU.
__global__ __launch_bounds__(256) void pv4(const __bf16* __restrict__ attn,
                                           const __bf16* __restrict__ vt,
                                           float* __restrict__ out) {
  __shared__ __bf16 sA[4 * 4096];
  __shared__ __bf16 sB[4 * 4096];
  const int raw = blockIdx.x;
  const int xcd = raw & 7, idx = raw >> 3;       // nwg=256
  const int rp = (xcd >> 1) * 8 + (idx >> 2);    // [0,32)
  const int cp = (xcd & 1) * 4 + (idx & 3);      // [0,8)
  const long row0 = (long)rp * 128;
  const long col0 = (long)cp * 128;
  const int tid = threadIdx.x;
  const int lane = tid & 63, w = tid >> 6;
  const int wr = w >> 1, wc = w & 1;
  const int lo = lane & 15, hi = lane >> 4;
  constexpr int NT = 128;

  auto stageA = [&](int buf, int kt) {
#pragma unroll
    for (int j = 0; j < 2; ++j) {
      int p = tid + j * 256;
      int row = p >> 2, cg = (p & 3) ^ ((row >> 1) & 3);
      gload_lds16(attn + (row0 + row) * 4096 + kt * 32 + cg * 8,
                  sA + buf * 4096 + p * 8);
    }
  };
  auto stageB = [&](int buf, int kt) {
#pragma unroll
    for (int j = 0; j < 2; ++j) {
      int p = tid + j * 256;
      int row = p >> 2, cg = (p & 3) ^ ((row >> 1) & 3);
      gload_lds16(vt + (col0 + row) * 4096 + kt * 32 + cg * 8,
                  sB + buf * 4096 + p * 8);
    }
  };

  f32x4 acc[4][4] = {};
#pragma unroll
  for (int t = 0; t < 3; ++t) { stageA(t, t); stageB(t, t); }
  WAITB(8);

#pragma unroll 4
  for (int t = 0; t < NT; ++t) {
    const int d = t & 3;
    const __bf16* sAc = sA + d * 4096;
    const __bf16* sBc = sB + d * 4096;
    const int s = (t + 3) & 3;
    bf16x8 af[4], bfr[4];
#pragma unroll
    for (int m = 0; m < 4; ++m) af[m] = LDS_FRAG(sAc, wr * 64 + m * 16 + lo);
#pragma unroll
    for (int n = 0; n < 4; ++n) bfr[n] = LDS_FRAG(sBc, wc * 64 + n * 16 + lo);
    if (t + 3 < NT) { stageA(s, t + 3); stageB(s, t + 3); }
    __builtin_amdgcn_s_barrier();
    __builtin_amdgcn_s_setprio(1);
#pragma unroll
    for (int m = 0; m < 4; ++m)
#pragma unroll
      for (int n = 0; n < 4; ++n)
        acc[m][n] = __builtin_amdgcn_mfma_f32_16x16x32_bf16(af[m], bfr[n], acc[m][n], 0, 0, 0);
    __builtin_amdgcn_s_setprio(0);
    if (t + 3 < NT)      { WAITB(8); }
    else if (t + 2 < NT) { WAITB(4); }
    else                 { WAITB(0); }
  }

#pragma unroll
  for (int m = 0; m < 4; ++m)
#pragma unroll
    for (int n = 0; n < 4; ++n)
#pragma unroll
      for (int i = 0; i < 4; ++i) {
        long r = row0 + wr * 64 + m * 16 + hi * 4 + i;
        long c = col0 + wc * 64 + n * 16 + lo;
        out[r * 1024 + c] = acc[m][n][i];
      }
}

// One block per row of bf16 sim (ld 4096): mask, stable softmax of row/32,
// write normalized attn bf16 IN-PLACE. (R6-proven, BW-roofline.)
__global__ __launch_bounds__(256) void softmax_rows(__bf16* __restrict__ sim,
                                                    const int* __restrict__ mask) {
  const int row = blockIdx.x;
  __bf16* rp = sim + (size_t)row * 4096;
  const int4* mrow = (const int4*)(mask + (size_t)row * 4096);
  const int tid = threadIdx.x;

  float vals[16];
  float lmax = -INFINITY;
#pragma unroll
  for (int j = 0; j < 2; ++j) {
    bf16x8 s = ((const bf16x8*)rp)[tid + 256 * j];
    int4 m0 = mrow[(tid + 256 * j) * 2];
    int4 m1 = mrow[(tid + 256 * j) * 2 + 1];
    float f[8];
#pragma unroll
    for (int e = 0; e < 8; ++e) f[e] = (float)s[e];
    f[0] = m0.x ? f[0] : -1e20f;  f[1] = m0.y ? f[1] : -1e20f;
    f[2] = m0.z ? f[2] : -1e20f;  f[3] = m0.w ? f[3] : -1e20f;
    f[4] = m1.x ? f[4] : -1e20f;  f[5] = m1.y ? f[5] : -1e20f;
    f[6] = m1.z ? f[6] : -1e20f;  f[7] = m1.w ? f[7] : -1e20f;
#pragma unroll
    for (int e = 0; e < 8; ++e) {
      vals[8 * j + e] = f[e];
      lmax = fmaxf(lmax, f[e]);
    }
  }
#pragma unroll
  for (int off = 32; off; off >>= 1) lmax = fmaxf(lmax, __shfl_xor(lmax, off));
  __shared__ float red[4];
  __shared__ float bro[2];
  if ((tid & 63) == 0) red[tid >> 6] = lmax;
  __syncthreads();
  if (tid == 0) bro[0] = fmaxf(fmaxf(red[0], red[1]), fmaxf(red[2], red[3]));
  __syncthreads();
  const float m = bro[0];

  float e[16];
  float lsum = 0.f;
#pragma unroll
  for (int j = 0; j < 16; ++j) {
    e[j] = __expf((vals[j] - m) * 0.03125f);
    lsum += e[j];
  }
#pragma unroll
  for (int off = 32; off; off >>= 1) lsum += __shfl_xor(lsum, off);
  if ((tid & 63) == 0) red[tid >> 6] = lsum;
  __syncthreads();
  if (tid == 0) bro[1] = red[0] + red[1] + red[2] + red[3];
  __syncthreads();
  const float inv = 1.0f / bro[1];

#pragma unroll
  for (int j = 0; j < 2; ++j) {
    bf16x8 o;
#pragma unroll
    for (int q = 0; q < 8; ++q) o[q] = (__bf16)(e[8 * j + q] * inv);
    ((bf16x8*)rp)[tid + 256 * j] = o;
  }
}

// Converts x, Wq, Wk, Wv to bf16.
__global__ __launch_bounds__(256) void cvt_all(const float* __restrict__ x,
                                               const float* __restrict__ wq,
                                               const float* __restrict__ wk,
                                               const float* __restrict__ wv,
                                               __bf16* __restrict__ xb,
                                               __bf16* __restrict__ wqb,
                                               __bf16* __restrict__ wkb,
                                               __bf16* __restrict__ wvb) {
  int b = blockIdx.x;
  const float* in;
  __bf16* out;
  int base;
  if (b < 4096)      { in = x;  out = xb;  base = b; }
  else if (b < 5120) { in = wq; out = wqb; base = b - 4096; }
  else if (b < 6144) { in = wk; out = wkb; base = b - 5120; }
  else               { in = wv; out = wvb; base = b - 6144; }
  int i = base * 256 + threadIdx.x;
  float4 f = ((const float4*)in)[i];
  bf16x4 o;
  o[0] = (__bf16)f.x; o[1] = (__bf16)f.y; o[2] = (__bf16)f.z; o[3] = (__bf16)f.w;
  ((bf16x4*)out)[i] = o;
}

extern "C" void kernel_launch(void* const* d_in, const int* in_sizes, int n_in,
                              void* d_out, int out_size, void* d_ws, size_t ws_size,
                              hipStream_t stream) {
  const float* x = (const float*)d_in[0];
  const int* mask = (const int*)d_in[1];
  const float* Wq = (const float*)d_in[2];
  const float* Wk = (const float*)d_in[3];
  const float* Wv = (const float*)d_in[4];
  float* out = (float*)d_out;

  // Workspace layout (70 MB):
  // [0,8M)   vT bf16    [8,16M)  x bf16
  // [16,18M) Wq bf16    [18,20M) Wk bf16   [20,22M) Wv bf16
  // [22,30M) q bf16     [30,38M) k bf16
  // [38,70M) sim bf16 (attn in-place after softmax, ld 4096)
  char* ws = (char*)d_ws;
  __bf16* vtb = (__bf16*)(ws);
  __bf16* xb  = (__bf16*)(ws + (8ull << 20));
  __bf16* wqb = (__bf16*)(ws + (16ull << 20));
  __bf16* wkb = (__bf16*)(ws + (18ull << 20));
  __bf16* wvb = (__bf16*)(ws + (20ull << 20));
  __bf16* qb  = (__bf16*)(ws + (22ull << 20));
  __bf16* kb  = (__bf16*)(ws + (30ull << 20));
  __bf16* sim = (__bf16*)(ws + (38ull << 20));

  cvt_all<<<7168, 256, 0, stream>>>(x, Wq, Wk, Wv, xb, wqb, wkb, wvb);

  // q, k, vT: 192 blocks of 256^2
  qkv8<<<192, 512, 0, stream>>>(xb, wqb, wkb, wvb, qb, kb, vtb);
  // sim = q k^T (4096x4096): 256 blocks, 2D XCD panel tiling
  qk8<<<256, 512, 0, stream>>>(qb, kb, sim);
  // masked stable softmax, normalized attn bf16 in-place
  softmax_rows<<<4096, 256, 0, stream>>>(sim, mask);
  // out = attn vT^T: 256 blocks, 4-wave 128x128, no split
  pv4<<<256, 256, 0, stream>>>(sim, vtb, out);
}

// Round 10
// 154.391 us; speedup vs baseline: 1.2739x; 1.0065x over previous
//
#include <hip/hip_runtime.h>
#include <hip/hip_bf16.h>
#include <math.h>

// SelfAttention: out = softmax(mask(q k^T)/32) v, q=xWq^T k=xWk^T v=xWv^T
// N=4096 tokens, E=1024. bf16 MFMA compute, fp32 accumulate.
// R10: pv = split-K x2 at 128^2 (grid 512 -> 2 blocks/CU, 2 waves/SIMD) +
//      reduce_add2; qk8 reverted to R7 1D panel map.

typedef __attribute__((ext_vector_type(8))) __bf16 bf16x8;
typedef __attribute__((ext_vector_type(4))) __bf16 bf16x4;
typedef __attribute__((ext_vector_type(4))) float f32x4;

__device__ __forceinline__ void gload_lds16(const void* g, void* l) {
  __builtin_amdgcn_global_load_lds(
      (__attribute__((address_space(1))) void*)(g),
      (__attribute__((address_space(3))) void*)(l), 16, 0, 0);
}

#define WAITB(N) asm volatile("s_waitcnt vmcnt(" #N ")\ns_barrier" ::: "memory")

// Swizzled ds_read of one bf16x8 fragment at (row r, k-chunk hi).
#define LDS_FRAG(base, r) \
  *(const bf16x8*)((base) + (r) * 32 + (((hi) ^ (((r) >> 1) & 3)) * 8))

#define MM16(mq, AF)                                                        \
  __builtin_amdgcn_s_setprio(1);                                            \
  _Pragma("unroll") for (int m = 0; m < 4; ++m)                             \
    _Pragma("unroll") for (int n = 0; n < 4; ++n)                           \
      acc[(mq) * 4 + m][n] = __builtin_amdgcn_mfma_f32_16x16x32_bf16(       \
          AF[m], bfr[n], acc[(mq) * 4 + m][n], 0, 0, 0);                    \
  __builtin_amdgcn_s_setprio(0);

// ---- 256x256 tile, BK=32, 8 waves (2M x 4N), 4-deep LDS pipeline ----
template <int NT>
__device__ __forceinline__ void g8_loop(const __bf16* __restrict__ A, long lda, long row0,
                                        const __bf16* __restrict__ B, long ldb, long col0,
                                        int kt0, __bf16* sA, __bf16* sB,
                                        f32x4 (&acc)[8][4], int tid) {
  const int lane = tid & 63;
  const int w = tid >> 6;
  const int wr = w >> 2, wc = w & 3;
  const int lo = lane & 15, hi = lane >> 4;

  auto stageA = [&](int buf, int kt) {
#pragma unroll
    for (int j = 0; j < 2; ++j) {
      int p = tid + j * 512;
      int row = p >> 2, cg = (p & 3) ^ ((row >> 1) & 3);
      gload_lds16(A + (row0 + row) * lda + kt * 32 + cg * 8,
                  sA + buf * 8192 + p * 8);
    }
  };
  auto stageB = [&](int buf, int kt) {
#pragma unroll
    for (int j = 0; j < 2; ++j) {
      int p = tid + j * 512;
      int row = p >> 2, cg = (p & 3) ^ ((row >> 1) & 3);
      gload_lds16(B + (col0 + row) * ldb + kt * 32 + cg * 8,
                  sB + buf * 8192 + p * 8);
    }
  };

#pragma unroll
  for (int t = 0; t < 3; ++t) { stageA(t, kt0 + t); stageB(t, kt0 + t); }
  WAITB(8);  // tile0 landed; tiles 1,2 in flight

  for (int t = 0; t < NT; ++t) {
    const int d = t & 3;
    const __bf16* sAc = sA + d * 8192;
    const __bf16* sBc = sB + d * 8192;
    const int s = (t + 3) & 3;
    bf16x8 af[4], bfr[4];
#pragma unroll
    for (int m = 0; m < 4; ++m) af[m] = LDS_FRAG(sAc, wr * 128 + m * 16 + lo);
#pragma unroll
    for (int n = 0; n < 4; ++n) bfr[n] = LDS_FRAG(sBc, wc * 64 + n * 16 + lo);
    if (t + 3 < NT) stageA(s, kt0 + t + 3);
    __builtin_amdgcn_s_barrier();
    MM16(0, af);
    __builtin_amdgcn_s_barrier();
    bf16x8 af2[4];
#pragma unroll
    for (int m = 0; m < 4; ++m) af2[m] = LDS_FRAG(sAc, wr * 128 + 64 + m * 16 + lo);
    if (t + 3 < NT) stageB(s, kt0 + t + 3);
    __builtin_amdgcn_s_barrier();
    MM16(1, af2);
    if (t + 3 < NT)      { WAITB(8); }
    else if (t + 2 < NT) { WAITB(4); }
    else                 { WAITB(0); }
  }
}

// ---------------- kernels ----------------

// Fused QKV. z=0: q = x Wq^T; z=1: k = x Wk^T; z=2: vT = Wv x^T.
__global__ __launch_bounds__(512) void qkv8(const __bf16* __restrict__ xb,
                                            const __bf16* __restrict__ wq,
                                            const __bf16* __restrict__ wk,
                                            const __bf16* __restrict__ wv,
                                            __bf16* __restrict__ qb,
                                            __bf16* __restrict__ kb,
                                            __bf16* __restrict__ vtb) {
  __shared__ __bf16 sA[4 * 8192];
  __shared__ __bf16 sB[4 * 8192];
  const int raw = blockIdx.x;
  const int wid = (raw & 7) * 24 + (raw >> 3);   // nwg=192, bijective
  const int z = wid >> 6;
  const int r2 = wid & 63;
  const int tid = threadIdx.x;
  const __bf16* A;
  const __bf16* B;
  long row0, col0;
  if (z == 2) {            // A = Wv, B = x  -> vT coalesced
    A = wv; B = xb;
    row0 = (long)(r2 >> 4) * 256;
    col0 = (long)(r2 & 15) * 256;
  } else {
    A = xb; B = (z == 0) ? wq : wk;
    row0 = (long)(r2 >> 2) * 256;
    col0 = (long)(r2 & 3) * 256;
  }
  f32x4 acc[8][4] = {};
  g8_loop<32>(A, 1024, row0, B, 1024, col0, 0, sA, sB, acc, tid);

  const int lane = tid & 63, w = tid >> 6;
  const int wr = w >> 2, wc = w & 3;
  const int lo = lane & 15, hi = lane >> 4;
#pragma unroll
  for (int m = 0; m < 8; ++m)
#pragma unroll
    for (int n = 0; n < 4; ++n)
#pragma unroll
      for (int i = 0; i < 4; ++i) {
        long r = row0 + wr * 128 + m * 16 + hi * 4 + i;
        long c = col0 + wc * 64 + n * 16 + lo;
        __bf16 v = (__bf16)acc[m][n][i];
        if (z == 0)      qb[r * 1024 + c] = v;
        else if (z == 1) kb[r * 1024 + c] = v;
        else             vtb[r * 4096 + c] = v;
      }
}

// sim = q k^T (bf16 out, ld 4096). R7 1D XCD map.
__global__ __launch_bounds__(512) void qk8(const __bf16* __restrict__ qb,
                                           const __bf16* __restrict__ kb,
                                           __bf16* __restrict__ sim) {
  __shared__ __bf16 sA[4 * 8192];
  __shared__ __bf16 sB[4 * 8192];
  const int raw = blockIdx.x;
  const int wid = (raw & 7) * 32 + (raw >> 3);   // nwg=256, bijective
  const long row0 = (long)(wid >> 4) * 256;
  const long col0 = (long)(wid & 15) * 256;
  const int tid = threadIdx.x;
  f32x4 acc[8][4] = {};
  g8_loop<32>(qb, 1024, row0, kb, 1024, col0, 0, sA, sB, acc, tid);

  const int lane = tid & 63, w = tid >> 6;
  const int wr = w >> 2, wc = w & 3;
  const int lo = lane & 15, hi = lane >> 4;
#pragma unroll
  for (int m = 0; m < 8; ++m)
#pragma unroll
    for (int n = 0; n < 4; ++n)
#pragma unroll
      for (int i = 0; i < 4; ++i) {
        long r = row0 + wr * 128 + m * 16 + hi * 4 + i;
        long c = col0 + wc * 64 + n * 16 + lo;
        sim[r * 4096 + c] = (__bf16)acc[m][n][i];
      }
}

// PV split-K x2: 128x128 tile, 4 waves (2x2 of 64x64), BK=32, NT=64.
// Grid 512 (32 rp x 8 cp x 2 z) -> 2 blocks/CU, 2 waves/SIMD.
__global__ __launch_bounds__(256) void pv4(const __bf16* __restrict__ attn,
                                           const __bf16* __restrict__ vt,
                                           float* __restrict__ out,
                                           float* __restrict__ p1) {
  __shared__ __bf16 sA[4 * 4096];
  __shared__ __bf16 sB[4 * 4096];
  const int raw = blockIdx.x;
  const int wid = (raw & 7) * 64 + (raw >> 3);   // nwg=512, bijective
  const int z = wid >> 8;
  const int r2 = wid & 255;
  const long row0 = (long)(r2 >> 3) * 128;       // token panel [0,32)
  const long col0 = (long)(r2 & 7) * 128;        // feature panel [0,8)
  float* C = z ? p1 : out;
  const int kt0 = z * 64;
  const int tid = threadIdx.x;
  const int lane = tid & 63, w = tid >> 6;
  const int wr = w >> 1, wc = w & 1;
  const int lo = lane & 15, hi = lane >> 4;
  constexpr int NT = 64;

  auto stageA = [&](int buf, int kt) {
#pragma unroll
    for (int j = 0; j < 2; ++j) {
      int p = tid + j * 256;
      int row = p >> 2, cg = (p & 3) ^ ((row >> 1) & 3);
      gload_lds16(attn + (row0 + row) * 4096 + kt * 32 + cg * 8,
                  sA + buf * 4096 + p * 8);
    }
  };
  auto stageB = [&](int buf, int kt) {
#pragma unroll
    for (int j = 0; j < 2; ++j) {
      int p = tid + j * 256;
      int row = p >> 2, cg = (p & 3) ^ ((row >> 1) & 3);
      gload_lds16(vt + (col0 + row) * 4096 + kt * 32 + cg * 8,
                  sB + buf * 4096 + p * 8);
    }
  };

  f32x4 acc[4][4] = {};
#pragma unroll
  for (int t = 0; t < 3; ++t) { stageA(t, kt0 + t); stageB(t, kt0 + t); }
  WAITB(8);

  for (int t = 0; t < NT; ++t) {
    const int d = t & 3;
    const __bf16* sAc = sA + d * 4096;
    const __bf16* sBc = sB + d * 4096;
    const int s = (t + 3) & 3;
    bf16x8 af[4], bfr[4];
#pragma unroll
    for (int m = 0; m < 4; ++m) af[m] = LDS_FRAG(sAc, wr * 64 + m * 16 + lo);
#pragma unroll
    for (int n = 0; n < 4; ++n) bfr[n] = LDS_FRAG(sBc, wc * 64 + n * 16 + lo);
    if (t + 3 < NT) { stageA(s, kt0 + t + 3); stageB(s, kt0 + t + 3); }
    __builtin_amdgcn_s_barrier();
    __builtin_amdgcn_s_setprio(1);
#pragma unroll
    for (int m = 0; m < 4; ++m)
#pragma unroll
      for (int n = 0; n < 4; ++n)
        acc[m][n] = __builtin_amdgcn_mfma_f32_16x16x32_bf16(af[m], bfr[n], acc[m][n], 0, 0, 0);
    __builtin_amdgcn_s_setprio(0);
    if (t + 3 < NT)      { WAITB(8); }
    else if (t + 2 < NT) { WAITB(4); }
    else                 { WAITB(0); }
  }

#pragma unroll
  for (int m = 0; m < 4; ++m)
#pragma unroll
    for (int n = 0; n < 4; ++n)
#pragma unroll
      for (int i = 0; i < 4; ++i) {
        long r = row0 + wr * 64 + m * 16 + hi * 4 + i;
        long c = col0 + wc * 64 + n * 16 + lo;
        C[r * 1024 + c] = acc[m][n][i];
      }
}

// out += p1
__global__ __launch_bounds__(256) void reduce_add2(float* __restrict__ out,
                                                   const float* __restrict__ p1) {
  int i = blockIdx.x * 256 + threadIdx.x;  // 1,048,576 float4s
  float4 a = ((const float4*)out)[i];
  float4 b = ((const float4*)p1)[i];
  a.x += b.x; a.y += b.y; a.z += b.z; a.w += b.w;
  ((float4*)out)[i] = a;
}

// One block per row of bf16 sim (ld 4096): mask, stable softmax of row/32,
// write normalized attn bf16 IN-PLACE.
__global__ __launch_bounds__(256) void softmax_rows(__bf16* __restrict__ sim,
                                                    const int* __restrict__ mask) {
  const int row = blockIdx.x;
  __bf16* rp = sim + (size_t)row * 4096;
  const int4* mrow = (const int4*)(mask + (size_t)row * 4096);
  const int tid = threadIdx.x;

  float vals[16];
  float lmax = -INFINITY;
#pragma unroll
  for (int j = 0; j < 2; ++j) {
    bf16x8 s = ((const bf16x8*)rp)[tid + 256 * j];
    int4 m0 = mrow[(tid + 256 * j) * 2];
    int4 m1 = mrow[(tid + 256 * j) * 2 + 1];
    float f[8];
#pragma unroll
    for (int e = 0; e < 8; ++e) f[e] = (float)s[e];
    f[0] = m0.x ? f[0] : -1e20f;  f[1] = m0.y ? f[1] : -1e20f;
    f[2] = m0.z ? f[2] : -1e20f;  f[3] = m0.w ? f[3] : -1e20f;
    f[4] = m1.x ? f[4] : -1e20f;  f[5] = m1.y ? f[5] : -1e20f;
    f[6] = m1.z ? f[6] : -1e20f;  f[7] = m1.w ? f[7] : -1e20f;
#pragma unroll
    for (int e = 0; e < 8; ++e) {
      vals[8 * j + e] = f[e];
      lmax = fmaxf(lmax, f[e]);
    }
  }
#pragma unroll
  for (int off = 32; off; off >>= 1) lmax = fmaxf(lmax, __shfl_xor(lmax, off));
  __shared__ float red[4];
  __shared__ float bro[2];
  if ((tid & 63) == 0) red[tid >> 6] = lmax;
  __syncthreads();
  if (tid == 0) bro[0] = fmaxf(fmaxf(red[0], red[1]), fmaxf(red[2], red[3]));
  __syncthreads();
  const float m = bro[0];

  float e[16];
  float lsum = 0.f;
#pragma unroll
  for (int j = 0; j < 16; ++j) {
    e[j] = __expf((vals[j] - m) * 0.03125f);
    lsum += e[j];
  }
#pragma unroll
  for (int off = 32; off; off >>= 1) lsum += __shfl_xor(lsum, off);
  if ((tid & 63) == 0) red[tid >> 6] = lsum;
  __syncthreads();
  if (tid == 0) bro[1] = red[0] + red[1] + red[2] + red[3];
  __syncthreads();
  const float inv = 1.0f / bro[1];

#pragma unroll
  for (int j = 0; j < 2; ++j) {
    bf16x8 o;
#pragma unroll
    for (int q = 0; q < 8; ++q) o[q] = (__bf16)(e[8 * j + q] * inv);
    ((bf16x8*)rp)[tid + 256 * j] = o;
  }
}

// Converts x, Wq, Wk, Wv to bf16.
__global__ __launch_bounds__(256) void cvt_all(const float* __restrict__ x,
                                               const float* __restrict__ wq,
                                               const float* __restrict__ wk,
                                               const float* __restrict__ wv,
                                               __bf16* __restrict__ xb,
                                               __bf16* __restrict__ wqb,
                                               __bf16* __restrict__ wkb,
                                               __bf16* __restrict__ wvb) {
  int b = blockIdx.x;
  const float* in;
  __bf16* out;
  int base;
  if (b < 4096)      { in = x;  out = xb;  base = b; }
  else if (b < 5120) { in = wq; out = wqb; base = b - 4096; }
  else if (b < 6144) { in = wk; out = wkb; base = b - 5120; }
  else               { in = wv; out = wvb; base = b - 6144; }
  int i = base * 256 + threadIdx.x;
  float4 f = ((const float4*)in)[i];
  bf16x4 o;
  o[0] = (__bf16)f.x; o[1] = (__bf16)f.y; o[2] = (__bf16)f.z; o[3] = (__bf16)f.w;
  ((bf16x4*)out)[i] = o;
}

extern "C" void kernel_launch(void* const* d_in, const int* in_sizes, int n_in,
                              void* d_out, int out_size, void* d_ws, size_t ws_size,
                              hipStream_t stream) {
  const float* x = (const float*)d_in[0];
  const int* mask = (const int*)d_in[1];
  const float* Wq = (const float*)d_in[2];
  const float* Wk = (const float*)d_in[3];
  const float* Wv = (const float*)d_in[4];
  float* out = (float*)d_out;

  // Workspace layout (70 MB):
  // [0,8M)   vT bf16    [8,16M)  x bf16
  // [16,18M) Wq bf16    [18,20M) Wk bf16   [20,22M) Wv bf16
  // [22,30M) q bf16     [30,38M) k bf16
  // [38,70M) sim bf16 (attn in-place after softmax, ld 4096)
  // PV-time (x,W dead): p1 [8,24M)
  char* ws = (char*)d_ws;
  __bf16* vtb = (__bf16*)(ws);
  __bf16* xb  = (__bf16*)(ws + (8ull << 20));
  __bf16* wqb = (__bf16*)(ws + (16ull << 20));
  __bf16* wkb = (__bf16*)(ws + (18ull << 20));
  __bf16* wvb = (__bf16*)(ws + (20ull << 20));
  __bf16* qb  = (__bf16*)(ws + (22ull << 20));
  __bf16* kb  = (__bf16*)(ws + (30ull << 20));
  __bf16* sim = (__bf16*)(ws + (38ull << 20));
  float*  p1  = (float*)(ws + (8ull << 20));

  cvt_all<<<7168, 256, 0, stream>>>(x, Wq, Wk, Wv, xb, wqb, wkb, wvb);

  // q, k, vT: 192 blocks of 256^2
  qkv8<<<192, 512, 0, stream>>>(xb, wqb, wkb, wvb, qb, kb, vtb);
  // sim = q k^T (4096x4096): 256 blocks
  qk8<<<256, 512, 0, stream>>>(qb, kb, sim);
  // masked stable softmax, normalized attn bf16 in-place
  softmax_rows<<<4096, 256, 0, stream>>>(sim, mask);
  // out = attn vT^T: split-K x2, 512 blocks (2/CU)
  pv4<<<512, 256, 0, stream>>>(sim, vtb, out, p1);
  reduce_add2<<<4096, 256, 0, stream>>>(out, p1);
}